// Round 1
// baseline (1057.666 us; speedup 1.0000x reference)
//
#include <hip/hip_runtime.h>

#define LRELU(x) ((x) > 0.0f ? (x) : 0.2f * (x))

// ---------------- conv 3x3 stride1 pad1, NCHW, 64x16x32x32 out ----------------
template<int CIN, bool RES>
__global__ __launch_bounds__(256) void conv3_k(
    const float* __restrict__ in, const float* __restrict__ wgt,
    const float* __restrict__ bias, const float* __restrict__ res,
    float* __restrict__ out)
{
    const int idx = blockIdx.x * 256 + threadIdx.x;          // b*16384 + co*1024 + h*32 + w
    const int w  = idx & 31;
    const int h  = (idx >> 5) & 31;
    const int co = (idx >> 10) & 15;
    const int b  = idx >> 14;

    float acc = bias[co];
    const float* wp = wgt + co * CIN * 9;
    const float* ip = in + ((long)b * CIN << 10);

    #pragma unroll
    for (int ci = 0; ci < CIN; ++ci) {
        #pragma unroll
        for (int kh = 0; kh < 3; ++kh) {
            const int ih = h + kh - 1;
            if (ih < 0 || ih > 31) continue;
            #pragma unroll
            for (int kw = 0; kw < 3; ++kw) {
                const int iw = w + kw - 1;
                if (iw < 0 || iw > 31) continue;
                acc += ip[(ci << 10) + (ih << 5) + iw] * wp[ci * 9 + kh * 3 + kw];
            }
        }
    }
    float v = LRELU(acc);
    if (RES) v += res[idx];
    out[idx] = v;
}

// ---------------- VQ: d2 = |x|^2 + |c|^2 - 2 x.c, first-min argmin ----------------
__global__ __launch_bounds__(256) void vq_k(
    const float* __restrict__ ze, const float* __restrict__ cb,
    float* __restrict__ zq, float* __restrict__ zst)
{
    const int n = blockIdx.x * 256 + threadIdx.x;            // pixel index b*1024 + h*32 + w
    const int base = ((n >> 10) << 14) + (n & 1023);         // NCHW addressing

    float x[16];
    float xx = 0.0f;
    #pragma unroll
    for (int c = 0; c < 16; ++c) {
        x[c] = ze[base + (c << 10)];
        xx += x[c] * x[c];
    }

    int best = 0;
    float bestd = 1e30f;
    #pragma unroll
    for (int k = 0; k < 10; ++k) {
        float dot = 0.0f, cn = 0.0f;
        #pragma unroll
        for (int c = 0; c < 16; ++c) {
            const float cv = cb[k * 16 + c];
            dot += x[c] * cv;
            cn  += cv * cv;
        }
        const float d2 = xx + cn - 2.0f * dot;
        if (d2 < bestd) { bestd = d2; best = k; }            // strict < : first min wins
    }

    #pragma unroll
    for (int c = 0; c < 16; ++c) {
        const float q = cb[best * 16 + c];
        zq[base + (c << 10)]  = q;
        zst[base + (c << 10)] = q + (x[c] - q);              // exactly as reference computes it
    }
}

// ---------------- fused per-pixel MLP decoder: 16 -> 256 -> 256 -> 784 ----------------
// One block = 32 pixels. g1/g2 tiles in LDS (64 KB). Register tiling 4 pixels x 8 cols.
__global__ __launch_bounds__(256) void decoder_k(
    const float* __restrict__ zst,
    const float* __restrict__ dw1, const float* __restrict__ db1,
    const float* __restrict__ dw2, const float* __restrict__ db2,
    const float* __restrict__ dw3, const float* __restrict__ db3,
    float* __restrict__ xrec)
{
    __shared__ float g1[32][256];
    __shared__ float g2[32][256];

    const int t = threadIdx.x;
    const int pix0 = blockIdx.x * 32;
    const int zbase = ((pix0 >> 10) << 14) + (pix0 & 1023);  // all 32 pixels share b

    // stage z tile [32 pixels][16 ch] into scratch at start of g2 (clobbered later by layer2)
    float* zs = &g2[0][0];
    for (int i = t; i < 512; i += 256) {
        const int p = i >> 4, c = i & 15;
        zs[i] = zst[zbase + (c << 10) + p];
    }
    __syncthreads();

    const int pg = t & 7;         // 8 pixel-groups of 4
    const int jg = t >> 3;        // 32 col-groups of 8
    const int p0 = pg * 4;
    const int j0 = jg * 8;

    // ---- layer 1: [32x16] @ dw1^T -> g1 [32x256] ----
    {
        float acc[4][8];
        #pragma unroll
        for (int jj = 0; jj < 8; ++jj) {
            const float bv = db1[j0 + jj];
            #pragma unroll
            for (int pp = 0; pp < 4; ++pp) acc[pp][jj] = bv;
        }
        #pragma unroll
        for (int c4 = 0; c4 < 4; ++c4) {
            float4 ga[4];
            #pragma unroll
            for (int pp = 0; pp < 4; ++pp)
                ga[pp] = *(const float4*)&zs[(p0 + pp) * 16 + c4 * 4];
            #pragma unroll
            for (int jj = 0; jj < 8; ++jj) {
                const float4 wv = *(const float4*)&dw1[(j0 + jj) * 16 + c4 * 4];
                #pragma unroll
                for (int pp = 0; pp < 4; ++pp)
                    acc[pp][jj] += ga[pp].x * wv.x + ga[pp].y * wv.y
                                 + ga[pp].z * wv.z + ga[pp].w * wv.w;
            }
        }
        __syncthreads();   // everyone done reading zs (lives in g2) and nobody reads g1 yet
        #pragma unroll
        for (int pp = 0; pp < 4; ++pp)
            #pragma unroll
            for (int jj = 0; jj < 8; ++jj) {
                const float a = acc[pp][jj];
                g1[p0 + pp][j0 + jj] = LRELU(a);
            }
    }
    __syncthreads();

    // ---- layer 2: g1 [32x256] @ dw2^T -> g2 [32x256] ----
    {
        float acc[4][8];
        #pragma unroll
        for (int jj = 0; jj < 8; ++jj) {
            const float bv = db2[j0 + jj];
            #pragma unroll
            for (int pp = 0; pp < 4; ++pp) acc[pp][jj] = bv;
        }
        for (int c4 = 0; c4 < 64; ++c4) {
            float4 ga[4];
            #pragma unroll
            for (int pp = 0; pp < 4; ++pp)
                ga[pp] = *(const float4*)&g1[p0 + pp][c4 * 4];
            #pragma unroll
            for (int jj = 0; jj < 8; ++jj) {
                const float4 wv = *(const float4*)&dw2[(j0 + jj) * 256 + c4 * 4];
                #pragma unroll
                for (int pp = 0; pp < 4; ++pp)
                    acc[pp][jj] += ga[pp].x * wv.x + ga[pp].y * wv.y
                                 + ga[pp].z * wv.z + ga[pp].w * wv.w;
            }
        }
        // writing g2 is safe: zs (in g2) is long dead, g1 untouched, g2 read only after next barrier
        #pragma unroll
        for (int pp = 0; pp < 4; ++pp)
            #pragma unroll
            for (int jj = 0; jj < 8; ++jj) {
                const float a = acc[pp][jj];
                g2[p0 + pp][j0 + jj] = LRELU(a);
            }
    }
    __syncthreads();

    // ---- layer 3: g2 [32x256] @ dw3^T -> sigmoid -> xrec [32x784] ----
    for (int ti = t; ti < 784; ti += 256) {               // 8 pgroups x 98 jgroups
        const int q0  = (ti & 7) * 4;
        const int jo0 = (ti >> 3) * 8;
        float acc[4][8];
        #pragma unroll
        for (int jj = 0; jj < 8; ++jj) {
            const float bv = db3[jo0 + jj];
            #pragma unroll
            for (int pp = 0; pp < 4; ++pp) acc[pp][jj] = bv;
        }
        for (int c4 = 0; c4 < 64; ++c4) {
            float4 ga[4];
            #pragma unroll
            for (int pp = 0; pp < 4; ++pp)
                ga[pp] = *(const float4*)&g2[q0 + pp][c4 * 4];
            #pragma unroll
            for (int jj = 0; jj < 8; ++jj) {
                const float4 wv = *(const float4*)&dw3[(jo0 + jj) * 256 + c4 * 4];
                #pragma unroll
                for (int pp = 0; pp < 4; ++pp)
                    acc[pp][jj] += ga[pp].x * wv.x + ga[pp].y * wv.y
                                 + ga[pp].z * wv.z + ga[pp].w * wv.w;
            }
        }
        #pragma unroll
        for (int pp = 0; pp < 4; ++pp) {
            const long n = pix0 + q0 + pp;
            float4 o1, o2;
            o1.x = 1.0f / (1.0f + __expf(-acc[pp][0]));
            o1.y = 1.0f / (1.0f + __expf(-acc[pp][1]));
            o1.z = 1.0f / (1.0f + __expf(-acc[pp][2]));
            o1.w = 1.0f / (1.0f + __expf(-acc[pp][3]));
            o2.x = 1.0f / (1.0f + __expf(-acc[pp][4]));
            o2.y = 1.0f / (1.0f + __expf(-acc[pp][5]));
            o2.z = 1.0f / (1.0f + __expf(-acc[pp][6]));
            o2.w = 1.0f / (1.0f + __expf(-acc[pp][7]));
            *(float4*)&xrec[n * 784 + jo0]     = o1;
            *(float4*)&xrec[n * 784 + jo0 + 4] = o2;
        }
    }
}

extern "C" void kernel_launch(void* const* d_in, const int* in_sizes, int n_in,
                              void* d_out, int out_size, void* d_ws, size_t ws_size,
                              hipStream_t stream) {
    const float* x    = (const float*)d_in[0];
    const float* cw1  = (const float*)d_in[1];
    const float* cb1  = (const float*)d_in[2];
    const float* cw2  = (const float*)d_in[3];
    const float* cb2  = (const float*)d_in[4];
    const float* r1w1 = (const float*)d_in[5];
    const float* r1b1 = (const float*)d_in[6];
    const float* r1w2 = (const float*)d_in[7];
    const float* r1b2 = (const float*)d_in[8];
    const float* r2w1 = (const float*)d_in[9];
    const float* r2b1 = (const float*)d_in[10];
    const float* r2w2 = (const float*)d_in[11];
    const float* r2b2 = (const float*)d_in[12];
    const float* cbk  = (const float*)d_in[13];
    const float* dw1  = (const float*)d_in[14];
    const float* db1  = (const float*)d_in[15];
    const float* dw2  = (const float*)d_in[16];
    const float* db2  = (const float*)d_in[17];
    const float* dw3  = (const float*)d_in[18];
    const float* db3  = (const float*)d_in[19];

    float* out  = (float*)d_out;
    float* xrec = out;                                   // [64*32*32, 784]
    float* ze   = out + 51380224;                        // [64,16,32,32]
    float* zst  = ze + 1048576;
    float* zq   = zst + 1048576;

    float* A = (float*)d_ws;                             // 3 x 4MB conv ping-pong buffers
    float* B = A + (1 << 20);
    float* C = B + (1 << 20);

    const int CG = 4096;                                 // 64*16*32*32 / 256

    conv3_k<1,  false><<<CG, 256, 0, stream>>>(x, cw1, cb1, nullptr, A);   // h1
    conv3_k<16, false><<<CG, 256, 0, stream>>>(A, cw2, cb2, nullptr, B);   // h2
    conv3_k<16, false><<<CG, 256, 0, stream>>>(B, r1w1, r1b1, nullptr, C); // t1
    conv3_k<16, true ><<<CG, 256, 0, stream>>>(C, r1w2, r1b2, B, A);       // h3 = lrelu(conv)+h2
    conv3_k<16, false><<<CG, 256, 0, stream>>>(A, r2w1, r2b1, nullptr, C); // t2
    conv3_k<16, true ><<<CG, 256, 0, stream>>>(C, r2w2, r2b2, A, ze);      // z_e -> d_out slice

    vq_k<<<256, 256, 0, stream>>>(ze, cbk, zq, zst);

    decoder_k<<<2048, 256, 0, stream>>>(zst, dw1, db1, dw2, db2, dw3, db3, xrec);
}

// Round 2
// 703.552 us; speedup vs baseline: 1.5033x; 1.5033x over previous
//
#include <hip/hip_runtime.h>

typedef __attribute__((ext_vector_type(8))) short bfrag;
typedef __attribute__((ext_vector_type(4))) float ffrag;

__device__ __forceinline__ float lrelu(float x) { return x > 0.f ? x : 0.2f * x; }

__device__ __forceinline__ short f2b(float f) {           // fp32 -> bf16 bits, RNE
    union { float f; unsigned u; } x; x.f = f;
    unsigned r = x.u + 0x7fffu + ((x.u >> 16) & 1u);
    return (short)(r >> 16);
}

// ---------------- weight prep: fp32 -> bf16 (dw1 zero-padded K 16->32) ----------------
__global__ __launch_bounds__(256) void prep_k(
    const float* __restrict__ dw1, const float* __restrict__ dw2, const float* __restrict__ dw3,
    short* __restrict__ dw1p, short* __restrict__ dw2b, short* __restrict__ dw3b)
{
    const int i = blockIdx.x * 256 + threadIdx.x;
    if (i < 65536)  dw2b[i] = f2b(dw2[i]);
    if (i < 200704) dw3b[i] = f2b(dw3[i]);
    if (i < 8192) {
        const int row = i >> 5, k = i & 31;
        dw1p[i] = (k < 16) ? f2b(dw1[row * 16 + k]) : (short)0;
    }
}

// ---------------- conv 3x3 s1 p1, NCHW. block = (image, 8-row band), 1 px x 16 co / thread ----
template<int CIN, bool RES>
__global__ __launch_bounds__(256) void conv3_k(
    const float* __restrict__ in, const float* __restrict__ wgt,
    const float* __restrict__ bias, const float* __restrict__ res,
    float* __restrict__ out)
{
    __shared__ float sin_[CIN][10][32];
    const int t = threadIdx.x;
    const int b = blockIdx.x >> 2;
    const int band = blockIdx.x & 3;
    const float* ip = in + (size_t)b * CIN * 1024;

    for (int i = t; i < CIN * 320; i += 256) {
        const int ci = i / 320, rem = i - ci * 320;
        const int rr = rem >> 5, c = rem & 31;
        const int row = band * 8 + rr - 1;
        sin_[ci][rr][c] = (row >= 0 && row < 32) ? ip[ci * 1024 + row * 32 + c] : 0.f;
    }
    __syncthreads();

    const int hl = t >> 5;          // 0..7
    const int w  = t & 31;
    float acc[16];
    #pragma unroll
    for (int co = 0; co < 16; ++co) acc[co] = bias[co];

    #pragma unroll
    for (int ci = 0; ci < CIN; ++ci)
        #pragma unroll
        for (int kh = 0; kh < 3; ++kh)
            #pragma unroll
            for (int kw = 0; kw < 3; ++kw) {
                const int iw = w + kw - 1;
                const float v = (iw >= 0 && iw < 32) ? sin_[ci][hl + kh][iw] : 0.f;
                #pragma unroll
                for (int co = 0; co < 16; ++co)   // weight index thread-uniform -> s_load
                    acc[co] = fmaf(v, wgt[(co * CIN + ci) * 9 + kh * 3 + kw], acc[co]);
            }

    const int obase = b * 16384 + (band * 8 + hl) * 32 + w;
    #pragma unroll
    for (int co = 0; co < 16; ++co) {
        float v = lrelu(acc[co]);
        if (RES) v += res[obase + co * 1024];
        out[obase + co * 1024] = v;
    }
}

// ---------------- VQ: fp32 argmin (first-min), writes zq/zst fp32 + zst bf16 [px][16] ----------
__global__ __launch_bounds__(256) void vq_k(
    const float* __restrict__ ze, const float* __restrict__ cb,
    float* __restrict__ zq, float* __restrict__ zst, short* __restrict__ zstb)
{
    const int n = blockIdx.x * 256 + threadIdx.x;
    const int base = ((n >> 10) << 14) + (n & 1023);

    float x[16]; float xx = 0.f;
    #pragma unroll
    for (int c = 0; c < 16; ++c) { x[c] = ze[base + (c << 10)]; xx += x[c] * x[c]; }

    int best = 0; float bestd = 1e30f;
    #pragma unroll
    for (int k = 0; k < 10; ++k) {
        float dot = 0.f, cn = 0.f;
        #pragma unroll
        for (int c = 0; c < 16; ++c) { const float cv = cb[k * 16 + c]; dot += x[c] * cv; cn += cv * cv; }
        const float d2 = xx + cn - 2.f * dot;
        if (d2 < bestd) { bestd = d2; best = k; }
    }

    unsigned pk[8];
    #pragma unroll
    for (int c = 0; c < 16; ++c) {
        const float q = cb[best * 16 + c];
        const float s = q + (x[c] - q);
        zq[base + (c << 10)]  = q;
        zst[base + (c << 10)] = s;
        const unsigned hb = (unsigned)(unsigned short)f2b(s);
        if (c & 1) pk[c >> 1] |= hb << 16; else pk[c >> 1] = hb;
    }
    uint4* d = (uint4*)(zstb + (size_t)n * 16);
    d[0] = make_uint4(pk[0], pk[1], pk[2], pk[3]);
    d[1] = make_uint4(pk[4], pk[5], pk[6], pk[7]);
}

// ---------------- fused MFMA decoder: 16 -> 256 -> 256 -> 784, tile = 64 px, 8 waves ----------
// wave grid: 2 rowgroups x 4 colgroups. LDS g1/g2 [64][256] bf16, XOR-swizzled (elem ^ (row&7)<<3).
__global__ __launch_bounds__(512, 4) void decoder_k(
    const short* __restrict__ zstb,
    const short* __restrict__ dw1p, const float* __restrict__ db1,
    const short* __restrict__ dw2b, const float* __restrict__ db2,
    const short* __restrict__ dw3b, const float* __restrict__ db3,
    float* __restrict__ xrec)
{
    __shared__ short g1[64 * 256];
    __shared__ short g2[64 * 256];
    short* zbuf = g2;                 // [64][32] bf16, dead before g2 is written

    const int t    = threadIdx.x;
    const int lane = t & 63;
    const int wid  = t >> 6;
    const int rg   = wid >> 2;        // 0..1 -> rows rg*32
    const int cg   = wid & 3;         // 0..3
    const int lr   = lane & 15;
    const int lg   = lane >> 4;       // k-group
    const int pix0 = blockIdx.x * 64;

    // ---- stage z tile: [64][32] bf16, k 16..31 zero, swizzle chunk ^ (row&3) ----
    if (t < 64) {
        const uint4* zp = (const uint4*)(zstb + (size_t)(pix0 + t) * 16);
        const uint4 a = zp[0], b = zp[1];
        const int s = t & 3;
        uint4* dst = (uint4*)(zbuf + t * 32);
        const uint4 zz = make_uint4(0, 0, 0, 0);
        dst[0 ^ s] = a; dst[1 ^ s] = b; dst[2 ^ s] = zz; dst[3 ^ s] = zz;
    }
    __syncthreads();

    // ---- layer 1: z[64x32] @ dw1p^T -> g1 ----
    {
        ffrag acc[2][4];
        int cols[4];
        #pragma unroll
        for (int c = 0; c < 4; ++c) {
            cols[c] = (cg * 4 + c) * 16 + lr;
            const float bv = db1[cols[c]];
            #pragma unroll
            for (int rt = 0; rt < 2; ++rt)
                #pragma unroll
                for (int q = 0; q < 4; ++q) acc[rt][c][q] = bv;
        }
        bfrag B[4];
        #pragma unroll
        for (int c = 0; c < 4; ++c)
            B[c] = *(const bfrag*)&dw1p[cols[c] * 32 + lg * 8];
        #pragma unroll
        for (int rt = 0; rt < 2; ++rt) {
            const int r = rg * 32 + rt * 16 + lr;
            const int kc = lg ^ (r & 3);
            const bfrag A = *(const bfrag*)&zbuf[r * 32 + kc * 8];
            #pragma unroll
            for (int c = 0; c < 4; ++c)
                acc[rt][c] = __builtin_amdgcn_mfma_f32_16x16x32_bf16(A, B[c], acc[rt][c], 0, 0, 0);
        }
        __syncthreads();   // all zbuf reads done before anyone writes g1/g2 regions further
        #pragma unroll
        for (int rt = 0; rt < 2; ++rt)
            #pragma unroll
            for (int c = 0; c < 4; ++c)
                #pragma unroll
                for (int q = 0; q < 4; ++q) {
                    const int R = rg * 32 + rt * 16 + lg * 4 + q;
                    g1[R * 256 + (cols[c] ^ ((R & 7) << 3))] = f2b(lrelu(acc[rt][c][q]));
                }
    }
    __syncthreads();

    // ---- layer 2: g1 @ dw2b^T -> g2 ----
    {
        ffrag acc[2][4];
        int cols[4];
        #pragma unroll
        for (int c = 0; c < 4; ++c) {
            cols[c] = (cg * 4 + c) * 16 + lr;
            const float bv = db2[cols[c]];
            #pragma unroll
            for (int rt = 0; rt < 2; ++rt)
                #pragma unroll
                for (int q = 0; q < 4; ++q) acc[rt][c][q] = bv;
        }
        #pragma unroll
        for (int kb = 0; kb < 256; kb += 32) {
            bfrag B[4];
            #pragma unroll
            for (int c = 0; c < 4; ++c)
                B[c] = *(const bfrag*)&dw2b[(size_t)cols[c] * 256 + kb + lg * 8];
            #pragma unroll
            for (int rt = 0; rt < 2; ++rt) {
                const int r = rg * 32 + rt * 16 + lr;
                const int kc = ((kb >> 3) + lg) ^ (r & 7);
                const bfrag A = *(const bfrag*)&g1[r * 256 + kc * 8];
                #pragma unroll
                for (int c = 0; c < 4; ++c)
                    acc[rt][c] = __builtin_amdgcn_mfma_f32_16x16x32_bf16(A, B[c], acc[rt][c], 0, 0, 0);
            }
        }
        __syncthreads();   // everyone done reading g1 AND zbuf(g2) before overwriting g2
        #pragma unroll
        for (int rt = 0; rt < 2; ++rt)
            #pragma unroll
            for (int c = 0; c < 4; ++c)
                #pragma unroll
                for (int q = 0; q < 4; ++q) {
                    const int R = rg * 32 + rt * 16 + lg * 4 + q;
                    g2[R * 256 + (cols[c] ^ ((R & 7) << 3))] = f2b(lrelu(acc[rt][c][q]));
                }
    }
    __syncthreads();

    // ---- layer 3: g2 @ dw3b^T -> sigmoid -> xrec. 49 col-tiles strided over 4 cgs ----
    const int nct = (cg == 0) ? 13 : 12;
    for (int i0 = 0; i0 < 13; i0 += 6) {
        if (i0 >= nct) break;
        ffrag acc[2][6];
        int cols[6]; bool val[6];
        #pragma unroll
        for (int c = 0; c < 6; ++c) {
            val[c] = (i0 + c) < nct;
            const int ct = cg + 4 * (i0 + c);
            cols[c] = val[c] ? (ct * 16 + lr) : 0;
            const float bv = val[c] ? db3[cols[c]] : 0.f;
            #pragma unroll
            for (int rt = 0; rt < 2; ++rt)
                #pragma unroll
                for (int q = 0; q < 4; ++q) acc[rt][c][q] = bv;
        }
        #pragma unroll
        for (int kb = 0; kb < 256; kb += 32) {
            bfrag B[6];
            #pragma unroll
            for (int c = 0; c < 6; ++c)
                if (val[c]) B[c] = *(const bfrag*)&dw3b[(size_t)cols[c] * 256 + kb + lg * 8];
            #pragma unroll
            for (int rt = 0; rt < 2; ++rt) {
                const int r = rg * 32 + rt * 16 + lr;
                const int kc = ((kb >> 3) + lg) ^ (r & 7);
                const bfrag A = *(const bfrag*)&g2[r * 256 + kc * 8];
                #pragma unroll
                for (int c = 0; c < 6; ++c)
                    if (val[c]) acc[rt][c] = __builtin_amdgcn_mfma_f32_16x16x32_bf16(A, B[c], acc[rt][c], 0, 0, 0);
            }
        }
        #pragma unroll
        for (int rt = 0; rt < 2; ++rt)
            #pragma unroll
            for (int c = 0; c < 6; ++c) {
                if (!val[c]) continue;
                #pragma unroll
                for (int q = 0; q < 4; ++q) {
                    const int R = pix0 + rg * 32 + rt * 16 + lg * 4 + q;
                    const float v = acc[rt][c][q];
                    xrec[(size_t)R * 784 + cols[c]] = 1.f / (1.f + __expf(-v));
                }
            }
    }
}

extern "C" void kernel_launch(void* const* d_in, const int* in_sizes, int n_in,
                              void* d_out, int out_size, void* d_ws, size_t ws_size,
                              hipStream_t stream) {
    const float* x    = (const float*)d_in[0];
    const float* cw1  = (const float*)d_in[1];
    const float* cb1  = (const float*)d_in[2];
    const float* cw2  = (const float*)d_in[3];
    const float* cb2  = (const float*)d_in[4];
    const float* r1w1 = (const float*)d_in[5];
    const float* r1b1 = (const float*)d_in[6];
    const float* r1w2 = (const float*)d_in[7];
    const float* r1b2 = (const float*)d_in[8];
    const float* r2w1 = (const float*)d_in[9];
    const float* r2b1 = (const float*)d_in[10];
    const float* r2w2 = (const float*)d_in[11];
    const float* r2b2 = (const float*)d_in[12];
    const float* cbk  = (const float*)d_in[13];
    const float* dw1  = (const float*)d_in[14];
    const float* db1  = (const float*)d_in[15];
    const float* dw2  = (const float*)d_in[16];
    const float* db2  = (const float*)d_in[17];
    const float* dw3  = (const float*)d_in[18];
    const float* db3  = (const float*)d_in[19];

    float* out  = (float*)d_out;
    float* xrec = out;                                   // [65536, 784]
    float* ze   = out + 51380224;                        // [64,16,32,32]
    float* zst  = ze + 1048576;
    float* zq   = zst + 1048576;

    float* A = (float*)d_ws;                             // 3 x 4MB conv ping-pong
    float* Bf = A + (1 << 20);
    float* Cf = Bf + (1 << 20);
    short* wsb  = (short*)(Cf + (1 << 20));              // bf16 area @ +12MB
    short* zstb = wsb;                                   // [65536][16]
    short* dw2b = zstb + 1048576;
    short* dw3b = dw2b + 65536;
    short* dw1p = dw3b + 200704;                         // [256][32] zero-padded

    prep_k<<<784, 256, 0, stream>>>(dw1, dw2, dw3, dw1p, dw2b, dw3b);

    conv3_k<1,  false><<<256, 256, 0, stream>>>(x,  cw1,  cb1,  nullptr, A);
    conv3_k<16, false><<<256, 256, 0, stream>>>(A,  cw2,  cb2,  nullptr, Bf);
    conv3_k<16, false><<<256, 256, 0, stream>>>(Bf, r1w1, r1b1, nullptr, Cf);
    conv3_k<16, true ><<<256, 256, 0, stream>>>(Cf, r1w2, r1b2, Bf, A);
    conv3_k<16, false><<<256, 256, 0, stream>>>(A,  r2w1, r2b1, nullptr, Cf);
    conv3_k<16, true ><<<256, 256, 0, stream>>>(Cf, r2w2, r2b2, A, ze);

    vq_k<<<256, 256, 0, stream>>>(ze, cbk, zq, zst, zstb);

    decoder_k<<<1024, 512, 0, stream>>>(zstb, dw1p, db1, dw2b, db2, dw3b, db3, xrec);
}

// Round 3
// 282.728 us; speedup vs baseline: 3.7409x; 2.4884x over previous
//
#include <hip/hip_runtime.h>

typedef __attribute__((ext_vector_type(8))) short bfrag;
typedef __attribute__((ext_vector_type(4))) float ffrag;

__device__ __forceinline__ float lrelu(float x) { return x > 0.f ? x : 0.2f * x; }

__device__ __forceinline__ short f2b(float f) {           // fp32 -> bf16 bits, RNE
    union { float f; unsigned u; } x; x.f = f;
    unsigned r = x.u + 0x7fffu + ((x.u >> 16) & 1u);
    return (short)(r >> 16);
}

// ---------------- weight prep: fp32 -> bf16 (dw1 zero-padded K 16->32) ----------------
__global__ __launch_bounds__(256) void prep_k(
    const float* __restrict__ dw1, const float* __restrict__ dw2, const float* __restrict__ dw3,
    short* __restrict__ dw1p, short* __restrict__ dw2b, short* __restrict__ dw3b)
{
    const int i = blockIdx.x * 256 + threadIdx.x;
    if (i < 65536)  dw2b[i] = f2b(dw2[i]);
    if (i < 200704) dw3b[i] = f2b(dw3[i]);
    if (i < 8192) {
        const int row = i >> 5, k = i & 31;
        dw1p[i] = (k < 16) ? f2b(dw1[row * 16 + k]) : (short)0;
    }
}

// ---------------- conv 3x3 s1 p1, NCHW ----------------
// grid = 64 img x 8 bands(4 rows). block 256 = w4(8) x co2(8) x row(4).
// Each thread: 4 px x 2 cout. Weights + haloed input in LDS.
template<int CIN, bool RES>
__global__ __launch_bounds__(256) void conv3_k(
    const float* __restrict__ in, const float* __restrict__ wgt,
    const float* __restrict__ bias, const float* __restrict__ res,
    float* __restrict__ out)
{
    __shared__ float sw[16 * CIN * 9];
    __shared__ float si[CIN][6][34];     // rows band*4-1..band*4+4, cols -1..32

    const int t = threadIdx.x;
    const int b = blockIdx.x >> 3;
    const int band = blockIdx.x & 7;
    const float* ip = in + (size_t)b * CIN * 1024;

    for (int i = t; i < 16 * CIN * 9; i += 256) sw[i] = wgt[i];
    for (int i = t; i < CIN * 204; i += 256) {
        const int ci = i / 204;
        const int rem = i - ci * 204;
        const int rr = rem / 34;
        const int cc = rem - rr * 34;
        const int row = band * 4 + rr - 1;
        const int cv  = cc - 1;
        si[ci][rr][cc] = (row >= 0 && row < 32 && cv >= 0 && cv < 32)
                       ? ip[ci * 1024 + row * 32 + cv] : 0.f;
    }
    __syncthreads();

    const int w4 = (t & 7) * 4;
    const int co = ((t >> 3) & 7) * 2;
    const int r  = t >> 6;

    float acc[2][4];
    #pragma unroll
    for (int j = 0; j < 2; ++j) {
        const float bv = bias[co + j];
        #pragma unroll
        for (int p = 0; p < 4; ++p) acc[j][p] = bv;
    }

    #pragma unroll
    for (int ci = 0; ci < CIN; ++ci)
        #pragma unroll
        for (int kh = 0; kh < 3; ++kh) {
            const float* srow = &si[ci][r + kh][w4];   // idx m -> col w4-1+m
            float v[6];
            #pragma unroll
            for (int m = 0; m < 6; ++m) v[m] = srow[m];
            #pragma unroll
            for (int j = 0; j < 2; ++j) {
                const float* wp = &sw[((co + j) * CIN + ci) * 9 + kh * 3];
                #pragma unroll
                for (int kw = 0; kw < 3; ++kw) {
                    const float wv = wp[kw];
                    #pragma unroll
                    for (int p = 0; p < 4; ++p)
                        acc[j][p] = fmaf(v[p + kw], wv, acc[j][p]);
                }
            }
        }

    const int row = band * 4 + r;
    #pragma unroll
    for (int j = 0; j < 2; ++j) {
        const size_t o = (size_t)b * 16384 + (size_t)(co + j) * 1024 + row * 32 + w4;
        float4 ov;
        ov.x = lrelu(acc[j][0]); ov.y = lrelu(acc[j][1]);
        ov.z = lrelu(acc[j][2]); ov.w = lrelu(acc[j][3]);
        if (RES) {
            const float4 rv = *(const float4*)&res[o];
            ov.x += rv.x; ov.y += rv.y; ov.z += rv.z; ov.w += rv.w;
        }
        *(float4*)&out[o] = ov;
    }
}

// ---------------- VQ: fp32 argmin (first-min), writes zq/zst fp32 + zst bf16 [px][16] ----------
__global__ __launch_bounds__(256) void vq_k(
    const float* __restrict__ ze, const float* __restrict__ cb,
    float* __restrict__ zq, float* __restrict__ zst, short* __restrict__ zstb)
{
    const int n = blockIdx.x * 256 + threadIdx.x;
    const int base = ((n >> 10) << 14) + (n & 1023);

    float x[16]; float xx = 0.f;
    #pragma unroll
    for (int c = 0; c < 16; ++c) { x[c] = ze[base + (c << 10)]; xx += x[c] * x[c]; }

    int best = 0; float bestd = 1e30f;
    #pragma unroll
    for (int k = 0; k < 10; ++k) {
        float dot = 0.f, cn = 0.f;
        #pragma unroll
        for (int c = 0; c < 16; ++c) { const float cv = cb[k * 16 + c]; dot += x[c] * cv; cn += cv * cv; }
        const float d2 = xx + cn - 2.f * dot;
        if (d2 < bestd) { bestd = d2; best = k; }
    }

    unsigned pk[8];
    #pragma unroll
    for (int c = 0; c < 16; ++c) {
        const float q = cb[best * 16 + c];
        const float s = q + (x[c] - q);
        zq[base + (c << 10)]  = q;
        zst[base + (c << 10)] = s;
        const unsigned hb = (unsigned)(unsigned short)f2b(s);
        if (c & 1) pk[c >> 1] |= hb << 16; else pk[c >> 1] = hb;
    }
    uint4* d = (uint4*)(zstb + (size_t)n * 16);
    d[0] = make_uint4(pk[0], pk[1], pk[2], pk[3]);
    d[1] = make_uint4(pk[4], pk[5], pk[6], pk[7]);
}

// ---------------- fused MFMA decoder: 16 -> 256 -> 256 -> 784, tile = 64 px, 8 waves ----------
// waves: 2 rowgroups x 4 colgroups. g1/g2 [64][256] bf16 XOR-swizzled (elem ^ (R&7)<<3).
// L3: 7 iters x 128 contiguous cols; results staged in LDS fp32, written as 512B runs.
__global__ __launch_bounds__(512, 2) void decoder_k(
    const short* __restrict__ zstb,
    const short* __restrict__ dw1p, const float* __restrict__ db1,
    const short* __restrict__ dw2b, const float* __restrict__ db2,
    const short* __restrict__ dw3b, const float* __restrict__ db3,
    float* __restrict__ xrec)
{
    __shared__ short g1[64 * 256];
    __shared__ short g2[64 * 256];
    short* zbuf  = g2;                 // [64][32] bf16, dead after L1
    float* stage = (float*)g1;         // [64][128] fp32 overlay, L3 only (g1 dead then)

    const int t    = threadIdx.x;
    const int lane = t & 63;
    const int wid  = t >> 6;
    const int rg   = wid >> 2;         // 0..1
    const int cg   = wid & 3;          // 0..3
    const int lr   = lane & 15;
    const int lg   = lane >> 4;
    const int pix0 = blockIdx.x * 64;

    // ---- stage z tile: [64][32] bf16, k 16..31 zero, chunk swizzle ^ (row&3) ----
    if (t < 64) {
        const uint4* zp = (const uint4*)(zstb + (size_t)(pix0 + t) * 16);
        const uint4 a = zp[0], b = zp[1];
        const int s = t & 3;
        uint4* dst = (uint4*)(zbuf + t * 32);
        const uint4 zz = make_uint4(0, 0, 0, 0);
        dst[0 ^ s] = a; dst[1 ^ s] = b; dst[2 ^ s] = zz; dst[3 ^ s] = zz;
    }
    __syncthreads();

    // ---- L1: z[64x32] @ dw1p^T -> g1 (each cg: 4 col-tiles) ----
    {
        ffrag acc[2][4];
        int cols[4];
        #pragma unroll
        for (int c = 0; c < 4; ++c) {
            cols[c] = (cg * 4 + c) * 16 + lr;
            const float bv = db1[cols[c]];
            #pragma unroll
            for (int rt = 0; rt < 2; ++rt)
                #pragma unroll
                for (int q = 0; q < 4; ++q) acc[rt][c][q] = bv;
        }
        bfrag B[4];
        #pragma unroll
        for (int c = 0; c < 4; ++c)
            B[c] = *(const bfrag*)&dw1p[cols[c] * 32 + lg * 8];
        #pragma unroll
        for (int rt = 0; rt < 2; ++rt) {
            const int r = rg * 32 + rt * 16 + lr;
            const int kc = lg ^ (r & 3);
            const bfrag A = *(const bfrag*)&zbuf[r * 32 + kc * 8];
            #pragma unroll
            for (int c = 0; c < 4; ++c)
                acc[rt][c] = __builtin_amdgcn_mfma_f32_16x16x32_bf16(A, B[c], acc[rt][c], 0, 0, 0);
        }
        __syncthreads();   // zbuf reads done
        #pragma unroll
        for (int rt = 0; rt < 2; ++rt)
            #pragma unroll
            for (int c = 0; c < 4; ++c)
                #pragma unroll
                for (int q = 0; q < 4; ++q) {
                    const int R = rg * 32 + rt * 16 + lg * 4 + q;
                    g1[R * 256 + (cols[c] ^ ((R & 7) << 3))] = f2b(lrelu(acc[rt][c][q]));
                }
    }
    __syncthreads();

    // ---- L2: g1 @ dw2b^T -> g2. 2 iters x (4cg x 2ct), A batch-loaded, reused across ct ----
    #pragma unroll
    for (int it = 0; it < 2; ++it) {
        ffrag acc[2][2];
        int col[2];
        #pragma unroll
        for (int c = 0; c < 2; ++c) {
            col[c] = (it * 8 + cg * 2 + c) * 16 + lr;
            const float bv = db2[col[c]];
            #pragma unroll
            for (int rt = 0; rt < 2; ++rt)
                #pragma unroll
                for (int q = 0; q < 4; ++q) acc[rt][c][q] = bv;
        }
        bfrag A[2][8];
        #pragma unroll
        for (int rt = 0; rt < 2; ++rt) {
            const int r = rg * 32 + rt * 16 + lr;
            #pragma unroll
            for (int kk = 0; kk < 8; ++kk) {
                const int kc = (kk * 4 + lg) ^ (r & 7);
                A[rt][kk] = *(const bfrag*)&g1[r * 256 + kc * 8];
            }
        }
        bfrag B[2][8];
        #pragma unroll
        for (int c = 0; c < 2; ++c)
            #pragma unroll
            for (int kk = 0; kk < 8; ++kk)
                B[c][kk] = *(const bfrag*)&dw2b[(size_t)col[c] * 256 + kk * 32 + lg * 8];
        #pragma unroll
        for (int kk = 0; kk < 8; ++kk)
            #pragma unroll
            for (int rt = 0; rt < 2; ++rt)
                #pragma unroll
                for (int c = 0; c < 2; ++c)
                    acc[rt][c] = __builtin_amdgcn_mfma_f32_16x16x32_bf16(A[rt][kk], B[c][kk], acc[rt][c], 0, 0, 0);
        // disjoint col regions per iter (swizzle stays within 128-col half) -> no sync needed
        #pragma unroll
        for (int rt = 0; rt < 2; ++rt)
            #pragma unroll
            for (int c = 0; c < 2; ++c)
                #pragma unroll
                for (int q = 0; q < 4; ++q) {
                    const int R = rg * 32 + rt * 16 + lg * 4 + q;
                    g2[R * 256 + (col[c] ^ ((R & 7) << 3))] = f2b(lrelu(acc[rt][c][q]));
                }
    }
    __syncthreads();

    // ---- L3: g2 @ dw3b^T -> sigmoid -> xrec. 7 iters x 128 cols, LDS-staged coalesced writes ----
    #pragma unroll 1
    for (int it = 0; it < 7; ++it) {
        const int T0 = it * 8 + cg * 2;
        ffrag acc[2][2];
        int col[2]; bool val[2];
        #pragma unroll
        for (int c = 0; c < 2; ++c) {
            val[c] = (T0 + c) < 49;
            col[c] = (T0 + c) * 16 + lr;
            const float bv = val[c] ? db3[col[c]] : 0.f;
            #pragma unroll
            for (int rt = 0; rt < 2; ++rt)
                #pragma unroll
                for (int q = 0; q < 4; ++q) acc[rt][c][q] = bv;
        }
        bfrag A[2][8];
        #pragma unroll
        for (int rt = 0; rt < 2; ++rt) {
            const int r = rg * 32 + rt * 16 + lr;
            #pragma unroll
            for (int kk = 0; kk < 8; ++kk) {
                const int kc = (kk * 4 + lg) ^ (r & 7);
                A[rt][kk] = *(const bfrag*)&g2[r * 256 + kc * 8];
            }
        }
        bfrag B[2][8];
        #pragma unroll
        for (int c = 0; c < 2; ++c)
            if (val[c])
                #pragma unroll
                for (int kk = 0; kk < 8; ++kk)
                    B[c][kk] = *(const bfrag*)&dw3b[(size_t)col[c] * 256 + kk * 32 + lg * 8];
        #pragma unroll
        for (int kk = 0; kk < 8; ++kk)
            #pragma unroll
            for (int rt = 0; rt < 2; ++rt)
                #pragma unroll
                for (int c = 0; c < 2; ++c)
                    if (val[c])
                        acc[rt][c] = __builtin_amdgcn_mfma_f32_16x16x32_bf16(A[rt][kk], B[c][kk], acc[rt][c], 0, 0, 0);

        __syncthreads();   // previous iter's stage reads complete
        #pragma unroll
        for (int rt = 0; rt < 2; ++rt)
            #pragma unroll
            for (int c = 0; c < 2; ++c) {
                if (!val[c]) continue;
                const int crel = (cg * 2 + c) * 16 + lr;
                #pragma unroll
                for (int q = 0; q < 4; ++q) {
                    const int Rl = rg * 32 + rt * 16 + lg * 4 + q;
                    stage[Rl * 128 + crel] = 1.f / (1.f + __expf(-acc[rt][c][q]));
                }
            }
        __syncthreads();

        const int nq = (it == 6) ? 4 : 32;            // float4s per row this iter
        const int total = 64 * nq;
        for (int idx = t; idx < total; idx += 512) {
            int row, cq;
            if (nq == 32) { row = idx >> 5; cq = idx & 31; }
            else          { row = idx >> 2; cq = idx & 3;  }
            const float4 v = *(const float4*)&stage[row * 128 + cq * 4];
            *(float4*)&xrec[(size_t)(pix0 + row) * 784 + it * 128 + cq * 4] = v;
        }
    }
}

extern "C" void kernel_launch(void* const* d_in, const int* in_sizes, int n_in,
                              void* d_out, int out_size, void* d_ws, size_t ws_size,
                              hipStream_t stream) {
    const float* x    = (const float*)d_in[0];
    const float* cw1  = (const float*)d_in[1];
    const float* cb1  = (const float*)d_in[2];
    const float* cw2  = (const float*)d_in[3];
    const float* cb2  = (const float*)d_in[4];
    const float* r1w1 = (const float*)d_in[5];
    const float* r1b1 = (const float*)d_in[6];
    const float* r1w2 = (const float*)d_in[7];
    const float* r1b2 = (const float*)d_in[8];
    const float* r2w1 = (const float*)d_in[9];
    const float* r2b1 = (const float*)d_in[10];
    const float* r2w2 = (const float*)d_in[11];
    const float* r2b2 = (const float*)d_in[12];
    const float* cbk  = (const float*)d_in[13];
    const float* dw1  = (const float*)d_in[14];
    const float* db1  = (const float*)d_in[15];
    const float* dw2  = (const float*)d_in[16];
    const float* db2  = (const float*)d_in[17];
    const float* dw3  = (const float*)d_in[18];
    const float* db3  = (const float*)d_in[19];

    float* out  = (float*)d_out;
    float* xrec = out;                                   // [65536, 784]
    float* ze   = out + 51380224;                        // [64,16,32,32]
    float* zst  = ze + 1048576;
    float* zq   = zst + 1048576;

    float* A  = (float*)d_ws;                            // 3 x 4MB conv ping-pong
    float* Bf = A + (1 << 20);
    float* Cf = Bf + (1 << 20);
    short* wsb  = (short*)(Cf + (1 << 20));              // bf16 area @ +12MB
    short* zstb = wsb;                                   // [65536][16]
    short* dw2b = zstb + 1048576;
    short* dw3b = dw2b + 65536;
    short* dw1p = dw3b + 200704;                         // [256][32] zero-padded

    prep_k<<<784, 256, 0, stream>>>(dw1, dw2, dw3, dw1p, dw2b, dw3b);

    conv3_k<1,  false><<<512, 256, 0, stream>>>(x,  cw1,  cb1,  nullptr, A);
    conv3_k<16, false><<<512, 256, 0, stream>>>(A,  cw2,  cb2,  nullptr, Bf);
    conv3_k<16, false><<<512, 256, 0, stream>>>(Bf, r1w1, r1b1, nullptr, Cf);
    conv3_k<16, true ><<<512, 256, 0, stream>>>(Cf, r1w2, r1b2, Bf, A);
    conv3_k<16, false><<<512, 256, 0, stream>>>(A,  r2w1, r2b1, nullptr, Cf);
    conv3_k<16, true ><<<512, 256, 0, stream>>>(Cf, r2w2, r2b2, A, ze);

    vq_k<<<256, 256, 0, stream>>>(ze, cbk, zq, zst, zstb);

    decoder_k<<<1024, 512, 0, stream>>>(zstb, dw1p, db1, dw2b, db2, dw3b, db3, xrec);
}

// Round 4
// 236.204 us; speedup vs baseline: 4.4778x; 1.1970x over previous
//
#include <hip/hip_runtime.h>

typedef __attribute__((ext_vector_type(8))) short bfrag;
typedef __attribute__((ext_vector_type(4))) float ffrag;

__device__ __forceinline__ float lrelu(float x) { return x > 0.f ? x : 0.2f * x; }

__device__ __forceinline__ short f2b(float f) {           // fp32 -> bf16 bits, RNE
    union { float f; unsigned u; } x; x.f = f;
    unsigned r = x.u + 0x7fffu + ((x.u >> 16) & 1u);
    return (short)(r >> 16);
}

// ---------------- weight prep: fp32 -> bf16 (dw1 zero-padded K 16->32) ----------------
__global__ __launch_bounds__(256) void prep_k(
    const float* __restrict__ dw1, const float* __restrict__ dw2, const float* __restrict__ dw3,
    short* __restrict__ dw1p, short* __restrict__ dw2b, short* __restrict__ dw3b)
{
    const int i = blockIdx.x * 256 + threadIdx.x;
    if (i < 65536)  dw2b[i] = f2b(dw2[i]);
    if (i < 200704) dw3b[i] = f2b(dw3[i]);
    if (i < 8192) {
        const int row = i >> 5, k = i & 31;
        dw1p[i] = (k < 16) ? f2b(dw1[row * 16 + k]) : (short)0;
    }
}

// ---------------- conv 3x3 s1 p1, NCHW. grid = 64 img x 16 bands(2 rows) ----------------
// block 256 = wpair(16) x row(2) x copair(8). Each thread: 2 px x 2 co.
template<int CIN, bool RES>
__global__ __launch_bounds__(256, 6) void conv3_k(
    const float* __restrict__ in, const float* __restrict__ wgt,
    const float* __restrict__ bias, const float* __restrict__ res,
    float* __restrict__ out)
{
    __shared__ float sw[16 * CIN * 9];
    __shared__ float si[CIN][4][34];     // rows band*2-1..band*2+2, cols -1..32

    const int t = threadIdx.x;
    const int b = blockIdx.x >> 4;
    const int band = blockIdx.x & 15;
    const float* ip = in + (size_t)b * CIN * 1024;

    for (int i = t; i < 16 * CIN * 9; i += 256) sw[i] = wgt[i];
    for (int i = t; i < CIN * 136; i += 256) {
        const int ci = i / 136;
        const int rem = i - ci * 136;
        const int rr = rem / 34;
        const int cc = rem - rr * 34;
        const int row = band * 2 + rr - 1;
        const int cv  = cc - 1;
        si[ci][rr][cc] = (row >= 0 && row < 32 && cv >= 0 && cv < 32)
                       ? ip[ci * 1024 + row * 32 + cv] : 0.f;
    }
    __syncthreads();

    const int w0 = (t & 15) * 2;
    const int rr = (t >> 4) & 1;
    const int co = (t >> 5) * 2;

    float acc[2][2];
    #pragma unroll
    for (int j = 0; j < 2; ++j) {
        const float bv = bias[co + j];
        acc[j][0] = bv; acc[j][1] = bv;
    }

    #pragma unroll
    for (int ci = 0; ci < CIN; ++ci)
        #pragma unroll
        for (int kh = 0; kh < 3; ++kh) {
            const float* srow = &si[ci][rr + kh][w0];   // idx m -> col w0-1+m
            float v[4];
            #pragma unroll
            for (int m = 0; m < 4; ++m) v[m] = srow[m];
            #pragma unroll
            for (int j = 0; j < 2; ++j) {
                const float* wp = &sw[((co + j) * CIN + ci) * 9 + kh * 3];
                #pragma unroll
                for (int kw = 0; kw < 3; ++kw) {
                    const float wv = wp[kw];
                    acc[j][0] = fmaf(v[kw],     wv, acc[j][0]);
                    acc[j][1] = fmaf(v[kw + 1], wv, acc[j][1]);
                }
            }
        }

    const int row = band * 2 + rr;
    #pragma unroll
    for (int j = 0; j < 2; ++j) {
        const size_t o = (size_t)b * 16384 + (size_t)(co + j) * 1024 + row * 32 + w0;
        float2 ov;
        ov.x = lrelu(acc[j][0]); ov.y = lrelu(acc[j][1]);
        if (RES) {
            const float2 rv = *(const float2*)&res[o];
            ov.x += rv.x; ov.y += rv.y;
        }
        *(float2*)&out[o] = ov;
    }
}

// ---------------- VQ: fp32 argmin (first-min), writes zq/zst fp32 + zst bf16 [px][16] ----------
__global__ __launch_bounds__(128) void vq_k(
    const float* __restrict__ ze, const float* __restrict__ cb,
    float* __restrict__ zq, float* __restrict__ zst, short* __restrict__ zstb)
{
    const int n = blockIdx.x * 128 + threadIdx.x;
    const int base = ((n >> 10) << 14) + (n & 1023);

    float x[16]; float xx = 0.f;
    #pragma unroll
    for (int c = 0; c < 16; ++c) { x[c] = ze[base + (c << 10)]; xx += x[c] * x[c]; }

    int best = 0; float bestd = 1e30f;
    #pragma unroll
    for (int k = 0; k < 10; ++k) {
        float dot = 0.f, cn = 0.f;
        #pragma unroll
        for (int c = 0; c < 16; ++c) { const float cv = cb[k * 16 + c]; dot += x[c] * cv; cn += cv * cv; }
        const float d2 = xx + cn - 2.f * dot;
        if (d2 < bestd) { bestd = d2; best = k; }
    }

    unsigned pk[8];
    #pragma unroll
    for (int c = 0; c < 16; ++c) {
        const float q = cb[best * 16 + c];
        const float s = q + (x[c] - q);
        zq[base + (c << 10)]  = q;
        zst[base + (c << 10)] = s;
        const unsigned hb = (unsigned)(unsigned short)f2b(s);
        if (c & 1) pk[c >> 1] |= hb << 16; else pk[c >> 1] = hb;
    }
    uint4* d = (uint4*)(zstb + (size_t)n * 16);
    d[0] = make_uint4(pk[0], pk[1], pk[2], pk[3]);
    d[1] = make_uint4(pk[4], pk[5], pk[6], pk[7]);
}

// ---------------- fused MFMA decoder: 16 -> 256 -> 256 -> 784 ----------------
// block = 256 thr = 4 waves (2 rg x 2 cg), tile = 64 px. ONE 32 KB LDS buffer reused:
// zbuf -> g1 -> g2 (in-place, A in regs between layers) -> wave-private fp32 slabs.
// L3 loop is barrier-free: each wave stages its own 32x32 output in its slab.
__global__ __launch_bounds__(256, 3) void decoder_k(
    const short* __restrict__ zstb,
    const short* __restrict__ dw1p, const float* __restrict__ db1,
    const short* __restrict__ dw2b, const float* __restrict__ db2,
    const short* __restrict__ dw3b, const float* __restrict__ db3,
    float* __restrict__ xrec)
{
    __shared__ short g[64 * 256];            // 32 KB, multi-purpose
    short* zbuf = g;                         // [64][32] bf16

    const int t    = threadIdx.x;
    const int lane = t & 63;
    const int wid  = t >> 6;
    const int rg   = wid >> 1;               // 0..1 -> rows rg*32
    const int cg   = wid & 1;                // 0..1
    const int lr   = lane & 15;
    const int lg   = lane >> 4;
    const int pix0 = blockIdx.x * 64;

    // ---- stage z tile: [64][32] bf16, k 16..31 zero, chunk swizzle ^ (row&3) ----
    if (t < 64) {
        const uint4* zp = (const uint4*)(zstb + (size_t)(pix0 + t) * 16);
        const uint4 a = zp[0], b = zp[1];
        const int s = t & 3;
        uint4* dst = (uint4*)(zbuf + t * 32);
        const uint4 zz = make_uint4(0, 0, 0, 0);
        dst[0 ^ s] = a; dst[1 ^ s] = b; dst[2 ^ s] = zz; dst[3 ^ s] = zz;
    }
    __syncthreads();

    // ---- L1: A from zbuf (regs), then write g1 over the same buffer ----
    {
        bfrag A1[2];
        #pragma unroll
        for (int rt = 0; rt < 2; ++rt) {
            const int r = rg * 32 + rt * 16 + lr;
            const int kc = lg ^ (r & 3);
            A1[rt] = *(const bfrag*)&zbuf[r * 32 + kc * 8];
        }
        __syncthreads();                     // zbuf fully consumed into regs
        #pragma unroll
        for (int j = 0; j < 8; ++j) {
            const int col = (cg * 8 + j) * 16 + lr;
            const bfrag B = *(const bfrag*)&dw1p[col * 32 + lg * 8];
            ffrag acc[2];
            const float bv = db1[col];
            #pragma unroll
            for (int rt = 0; rt < 2; ++rt) {
                #pragma unroll
                for (int q = 0; q < 4; ++q) acc[rt][q] = bv;
                acc[rt] = __builtin_amdgcn_mfma_f32_16x16x32_bf16(A1[rt], B, acc[rt], 0, 0, 0);
            }
            #pragma unroll
            for (int rt = 0; rt < 2; ++rt)
                #pragma unroll
                for (int q = 0; q < 4; ++q) {
                    const int R = rg * 32 + rt * 16 + lg * 4 + q;
                    g[R * 256 + (col ^ ((R & 7) << 3))] = f2b(lrelu(acc[rt][q]));
                }
        }
    }
    __syncthreads();

    // ---- L2: A (full K=256) from g1 into regs, then write g2 in-place ----
    {
        bfrag A2[2][8];
        #pragma unroll
        for (int rt = 0; rt < 2; ++rt) {
            const int r = rg * 32 + rt * 16 + lr;
            #pragma unroll
            for (int kk = 0; kk < 8; ++kk) {
                const int kc = (kk * 4 + lg) ^ (r & 7);
                A2[rt][kk] = *(const bfrag*)&g[r * 256 + kc * 8];
            }
        }
        __syncthreads();                     // g1 fully consumed into regs
        #pragma unroll
        for (int j = 0; j < 8; ++j) {
            const int col = (cg * 8 + j) * 16 + lr;
            ffrag acc[2];
            const float bv = db2[col];
            #pragma unroll
            for (int rt = 0; rt < 2; ++rt)
                #pragma unroll
                for (int q = 0; q < 4; ++q) acc[rt][q] = bv;
            bfrag B[8];
            #pragma unroll
            for (int kk = 0; kk < 8; ++kk)
                B[kk] = *(const bfrag*)&dw2b[(size_t)col * 256 + kk * 32 + lg * 8];
            #pragma unroll
            for (int kk = 0; kk < 8; ++kk)
                #pragma unroll
                for (int rt = 0; rt < 2; ++rt)
                    acc[rt] = __builtin_amdgcn_mfma_f32_16x16x32_bf16(A2[rt][kk], B[kk], acc[rt], 0, 0, 0);
            #pragma unroll
            for (int rt = 0; rt < 2; ++rt)
                #pragma unroll
                for (int q = 0; q < 4; ++q) {
                    const int R = rg * 32 + rt * 16 + lg * 4 + q;
                    g[R * 256 + (col ^ ((R & 7) << 3))] = f2b(lrelu(acc[rt][q]));
                }
        }
    }
    __syncthreads();

    // ---- L3: A from g2 into regs; g becomes wave-private slabs; NO barriers in loop ----
    bfrag A3[2][8];
    #pragma unroll
    for (int rt = 0; rt < 2; ++rt) {
        const int r = rg * 32 + rt * 16 + lr;
        #pragma unroll
        for (int kk = 0; kk < 8; ++kk) {
            const int kc = (kk * 4 + lg) ^ (r & 7);
            A3[rt][kk] = *(const bfrag*)&g[r * 256 + kc * 8];
        }
    }
    __syncthreads();                         // g2 fully consumed into regs

    float* slab = (float*)g + wid * 1152;    // [32][36] fp32, wave-private

    for (int p = cg; p <= 24; p += 2) {      // 24 full pairs of col-tiles + tail (p==24, cg0)
        const int nct = (p == 24) ? 1 : 2;
        ffrag acc[2][2];
        int col[2];
        #pragma unroll
        for (int c = 0; c < 2; ++c) {
            if (c >= nct) continue;
            col[c] = (p * 2 + c) * 16 + lr;
            const float bv = db3[col[c]];
            #pragma unroll
            for (int rt = 0; rt < 2; ++rt)
                #pragma unroll
                for (int q = 0; q < 4; ++q) acc[rt][c][q] = bv;
        }
        #pragma unroll
        for (int half = 0; half < 2; ++half) {
            bfrag B[2][4];
            #pragma unroll
            for (int c = 0; c < 2; ++c)
                if (c < nct)
                    #pragma unroll
                    for (int kk = 0; kk < 4; ++kk)
                        B[c][kk] = *(const bfrag*)&dw3b[(size_t)col[c] * 256 + (half * 4 + kk) * 32 + lg * 8];
            #pragma unroll
            for (int kk = 0; kk < 4; ++kk)
                #pragma unroll
                for (int rt = 0; rt < 2; ++rt)
                    #pragma unroll
                    for (int c = 0; c < 2; ++c)
                        if (c < nct)
                            acc[rt][c] = __builtin_amdgcn_mfma_f32_16x16x32_bf16(
                                A3[rt][half * 4 + kk], B[c][kk], acc[rt][c], 0, 0, 0);
        }
        // sigmoid -> wave-private slab (stride 36: conflict-free)
        #pragma unroll
        for (int rt = 0; rt < 2; ++rt)
            #pragma unroll
            for (int c = 0; c < 2; ++c) {
                if (c >= nct) continue;
                #pragma unroll
                for (int q = 0; q < 4; ++q) {
                    const int rl = rt * 16 + lg * 4 + q;
                    slab[rl * 36 + c * 16 + lr] = 1.f / (1.f + __expf(-acc[rt][c][q]));
                }
            }
        // wave-local copy out: rows of 128B (64B for tail)
        const int nq = nct * 4;                       // float4 per row
        const int tot = 32 * nq;
        for (int f = lane; f < tot; f += 64) {
            const int row = f / nq, c4 = f % nq;
            const float4 v = *(const float4*)&slab[row * 36 + c4 * 4];
            *(float4*)&xrec[(size_t)(pix0 + rg * 32 + row) * 784 + p * 32 + c4 * 4] = v;
        }
    }
}

extern "C" void kernel_launch(void* const* d_in, const int* in_sizes, int n_in,
                              void* d_out, int out_size, void* d_ws, size_t ws_size,
                              hipStream_t stream) {
    const float* x    = (const float*)d_in[0];
    const float* cw1  = (const float*)d_in[1];
    const float* cb1  = (const float*)d_in[2];
    const float* cw2  = (const float*)d_in[3];
    const float* cb2  = (const float*)d_in[4];
    const float* r1w1 = (const float*)d_in[5];
    const float* r1b1 = (const float*)d_in[6];
    const float* r1w2 = (const float*)d_in[7];
    const float* r1b2 = (const float*)d_in[8];
    const float* r2w1 = (const float*)d_in[9];
    const float* r2b1 = (const float*)d_in[10];
    const float* r2w2 = (const float*)d_in[11];
    const float* r2b2 = (const float*)d_in[12];
    const float* cbk  = (const float*)d_in[13];
    const float* dw1  = (const float*)d_in[14];
    const float* db1  = (const float*)d_in[15];
    const float* dw2  = (const float*)d_in[16];
    const float* db2  = (const float*)d_in[17];
    const float* dw3  = (const float*)d_in[18];
    const float* db3  = (const float*)d_in[19];

    float* out  = (float*)d_out;
    float* xrec = out;                                   // [65536, 784]
    float* ze   = out + 51380224;                        // [64,16,32,32]
    float* zst  = ze + 1048576;
    float* zq   = zst + 1048576;

    float* A  = (float*)d_ws;                            // 3 x 4MB conv ping-pong
    float* Bf = A + (1 << 20);
    float* Cf = Bf + (1 << 20);
    short* wsb  = (short*)(Cf + (1 << 20));              // bf16 area @ +12MB
    short* zstb = wsb;                                   // [65536][16]
    short* dw2b = zstb + 1048576;
    short* dw3b = dw2b + 65536;
    short* dw1p = dw3b + 200704;                         // [256][32] zero-padded

    prep_k<<<784, 256, 0, stream>>>(dw1, dw2, dw3, dw1p, dw2b, dw3b);

    conv3_k<1,  false><<<1024, 256, 0, stream>>>(x,  cw1,  cb1,  nullptr, A);
    conv3_k<16, false><<<1024, 256, 0, stream>>>(A,  cw2,  cb2,  nullptr, Bf);
    conv3_k<16, false><<<1024, 256, 0, stream>>>(Bf, r1w1, r1b1, nullptr, Cf);
    conv3_k<16, true ><<<1024, 256, 0, stream>>>(Cf, r1w2, r1b2, Bf, A);
    conv3_k<16, false><<<1024, 256, 0, stream>>>(A,  r2w1, r2b1, nullptr, Cf);
    conv3_k<16, true ><<<1024, 256, 0, stream>>>(Cf, r2w2, r2b2, A, ze);

    vq_k<<<512, 128, 0, stream>>>(ze, cbk, zq, zst, zstb);

    decoder_k<<<1024, 256, 0, stream>>>(zstb, dw1p, db1, dw2b, db2, dw3b, db3, xrec);
}

// Round 5
// 230.339 us; speedup vs baseline: 4.5918x; 1.0255x over previous
//
#include <hip/hip_runtime.h>

typedef __attribute__((ext_vector_type(8))) short bfrag;
typedef __attribute__((ext_vector_type(4))) float ffrag;

__device__ __forceinline__ float lrelu(float x) { return x > 0.f ? x : 0.2f * x; }

__device__ __forceinline__ short f2b(float f) {           // fp32 -> bf16 bits, RNE
    union { float f; unsigned u; } x; x.f = f;
    unsigned r = x.u + 0x7fffu + ((x.u >> 16) & 1u);
    return (short)(r >> 16);
}

// ---------------- weight prep: fp32 -> bf16 (dw1 zero-padded K 16->32) ----------------
__global__ __launch_bounds__(256) void prep_k(
    const float* __restrict__ dw1, const float* __restrict__ dw2, const float* __restrict__ dw3,
    short* __restrict__ dw1p, short* __restrict__ dw2b, short* __restrict__ dw3b)
{
    const int i = blockIdx.x * 256 + threadIdx.x;
    if (i < 65536)  dw2b[i] = f2b(dw2[i]);
    if (i < 200704) dw3b[i] = f2b(dw3[i]);
    if (i < 8192) {
        const int row = i >> 5, k = i & 31;
        dw1p[i] = (k < 16) ? f2b(dw1[row * 16 + k]) : (short)0;
    }
}

// ---------------- conv 3x3 s1 p1, NCHW. grid = 64 img x 16 bands(2 rows) ----------------
// block 256 = wpair(16) x row(2) x copair(8). Each thread: 2 px x 2 co.
// VQ=true: fused VQ epilogue (argmin + zq/zst/zstb) using the band's 64 px in LDS.
template<int CIN, bool RES, bool VQ>
__global__ __launch_bounds__(256, 6) void conv3_k(
    const float* __restrict__ in, const float* __restrict__ wgt,
    const float* __restrict__ bias, const float* __restrict__ res,
    float* __restrict__ out,
    const float* __restrict__ cbk, float* __restrict__ zq,
    float* __restrict__ zst, short* __restrict__ zstb)
{
    __shared__ float sw[16 * CIN * 9];
    __shared__ float si[CIN][4][34];            // rows band*2-1..band*2+2, cols -1..32
    __shared__ float sx[VQ ? 64 * 17 : 1];      // [px][ch] pad17
    __shared__ float scb[VQ ? 160 : 1];
    __shared__ int   sbest[VQ ? 64 : 1];

    const int t = threadIdx.x;
    const int b = blockIdx.x >> 4;
    const int band = blockIdx.x & 15;
    const float* ip = in + (size_t)b * CIN * 1024;

    for (int i = t; i < 16 * CIN * 9; i += 256) sw[i] = wgt[i];
    if (VQ) { if (t < 160) scb[t] = cbk[t]; }
    for (int i = t; i < CIN * 136; i += 256) {
        const int ci = i / 136;
        const int rem = i - ci * 136;
        const int rr = rem / 34;
        const int cc = rem - rr * 34;
        const int row = band * 2 + rr - 1;
        const int cv  = cc - 1;
        si[ci][rr][cc] = (row >= 0 && row < 32 && cv >= 0 && cv < 32)
                       ? ip[ci * 1024 + row * 32 + cv] : 0.f;
    }
    __syncthreads();

    const int w0 = (t & 15) * 2;
    const int rr = (t >> 4) & 1;
    const int co = (t >> 5) * 2;

    float acc[2][2];
    #pragma unroll
    for (int j = 0; j < 2; ++j) {
        const float bv = bias[co + j];
        acc[j][0] = bv; acc[j][1] = bv;
    }

    #pragma unroll
    for (int ci = 0; ci < CIN; ++ci)
        #pragma unroll
        for (int kh = 0; kh < 3; ++kh) {
            const float* srow = &si[ci][rr + kh][w0];   // idx m -> col w0-1+m
            float v[4];
            #pragma unroll
            for (int m = 0; m < 4; ++m) v[m] = srow[m];
            #pragma unroll
            for (int j = 0; j < 2; ++j) {
                const float* wp = &sw[((co + j) * CIN + ci) * 9 + kh * 3];
                #pragma unroll
                for (int kw = 0; kw < 3; ++kw) {
                    const float wv = wp[kw];
                    acc[j][0] = fmaf(v[kw],     wv, acc[j][0]);
                    acc[j][1] = fmaf(v[kw + 1], wv, acc[j][1]);
                }
            }
        }

    const int row = band * 2 + rr;
    #pragma unroll
    for (int j = 0; j < 2; ++j) {
        const size_t o = (size_t)b * 16384 + (size_t)(co + j) * 1024 + row * 32 + w0;
        float2 ov;
        ov.x = lrelu(acc[j][0]); ov.y = lrelu(acc[j][1]);
        if (RES) {
            const float2 rv = *(const float2*)&res[o];
            ov.x += rv.x; ov.y += rv.y;
        }
        *(float2*)&out[o] = ov;
        if (VQ) {
            sx[(rr * 32 + w0)     * 17 + co + j] = ov.x;
            sx[(rr * 32 + w0 + 1) * 17 + co + j] = ov.y;
        }
    }

    if (VQ) {
        __syncthreads();
        if (t < 64) {                          // one px per thread: argmin (first-min)
            float x[16]; float xx = 0.f;
            #pragma unroll
            for (int c = 0; c < 16; ++c) { x[c] = sx[t * 17 + c]; xx += x[c] * x[c]; }
            int best = 0; float bestd = 1e30f;
            #pragma unroll
            for (int k = 0; k < 10; ++k) {
                float dot = 0.f, cn = 0.f;
                #pragma unroll
                for (int c = 0; c < 16; ++c) { const float cv = scb[k * 16 + c]; dot += x[c] * cv; cn += cv * cv; }
                const float d2 = xx + cn - 2.f * dot;
                if (d2 < bestd) { bestd = d2; best = k; }
            }
            sbest[t] = best;
            unsigned pk[8];
            #pragma unroll
            for (int c = 0; c < 16; ++c) {
                const float q = scb[best * 16 + c];
                const float s = q + (x[c] - q);
                const unsigned hb = (unsigned)(unsigned short)f2b(s);
                if (c & 1) pk[c >> 1] |= hb << 16; else pk[c >> 1] = hb;
            }
            const size_t n = (size_t)b * 1024 + (band * 2 + (t >> 5)) * 32 + (t & 31);
            uint4* d = (uint4*)(zstb + n * 16);
            d[0] = make_uint4(pk[0], pk[1], pk[2], pk[3]);
            d[1] = make_uint4(pk[4], pk[5], pk[6], pk[7]);
        }
        __syncthreads();
        // coalesced zq/zst: 1024 elems = 16ch x 2rows x 32w, 256B runs per channel
        for (int i = t; i < 1024; i += 256) {
            const int c  = i >> 6;
            const int rw = i & 63;             // px in band
            const float q = scb[sbest[rw] * 16 + c];
            const float x = sx[rw * 17 + c];
            const size_t a = (size_t)b * 16384 + (size_t)c * 1024 + band * 64 + rw;
            zq[a]  = q;
            zst[a] = q + (x - q);
        }
    }
}

// ---------------- fused MFMA decoder: 16 -> 256 -> 256 -> 784 ----------------
// block = 256 thr = 4 waves (2 rg x 2 cg), tile = 64 px. ONE 32 KB LDS buffer reused:
// zbuf -> g1 -> g2 (in-place, A in regs between layers) -> wave-private fp32 slabs.
// L2/L3 software-pipelined: B-panel register double-buffer, prefetch depth 1.
__global__ __launch_bounds__(256, 3) void decoder_k(
    const short* __restrict__ zstb,
    const short* __restrict__ dw1p, const float* __restrict__ db1,
    const short* __restrict__ dw2b, const float* __restrict__ db2,
    const short* __restrict__ dw3b, const float* __restrict__ db3,
    float* __restrict__ xrec)
{
    __shared__ short g[64 * 256];            // 32 KB, multi-purpose
    short* zbuf = g;                         // [64][32] bf16

    const int t    = threadIdx.x;
    const int lane = t & 63;
    const int wid  = t >> 6;
    const int rg   = wid >> 1;               // 0..1 -> rows rg*32
    const int cg   = wid & 1;                // 0..1
    const int lr   = lane & 15;
    const int lg   = lane >> 4;
    const int pix0 = blockIdx.x * 64;

    auto loadB = [&](bfrag* dst, const short* wb, int colx) {
        #pragma unroll
        for (int kk = 0; kk < 8; ++kk)
            dst[kk] = *(const bfrag*)&wb[(size_t)colx * 256 + kk * 32 + lg * 8];
    };

    // ---- stage z tile: [64][32] bf16, k 16..31 zero, chunk swizzle ^ (row&3) ----
    if (t < 64) {
        const uint4* zp = (const uint4*)(zstb + (size_t)(pix0 + t) * 16);
        const uint4 a = zp[0], b = zp[1];
        const int s = t & 3;
        uint4* dst = (uint4*)(zbuf + t * 32);
        const uint4 zz = make_uint4(0, 0, 0, 0);
        dst[0 ^ s] = a; dst[1 ^ s] = b; dst[2 ^ s] = zz; dst[3 ^ s] = zz;
    }
    __syncthreads();

    // ---- L1: A from zbuf (regs), then write g1 over the same buffer ----
    {
        bfrag A1[2];
        #pragma unroll
        for (int rt = 0; rt < 2; ++rt) {
            const int r = rg * 32 + rt * 16 + lr;
            const int kc = lg ^ (r & 3);
            A1[rt] = *(const bfrag*)&zbuf[r * 32 + kc * 8];
        }
        __syncthreads();                     // zbuf fully consumed into regs
        #pragma unroll
        for (int j = 0; j < 8; ++j) {
            const int col = (cg * 8 + j) * 16 + lr;
            const bfrag B = *(const bfrag*)&dw1p[col * 32 + lg * 8];
            ffrag acc[2];
            const float bv = db1[col];
            #pragma unroll
            for (int rt = 0; rt < 2; ++rt) {
                #pragma unroll
                for (int q = 0; q < 4; ++q) acc[rt][q] = bv;
                acc[rt] = __builtin_amdgcn_mfma_f32_16x16x32_bf16(A1[rt], B, acc[rt], 0, 0, 0);
            }
            #pragma unroll
            for (int rt = 0; rt < 2; ++rt)
                #pragma unroll
                for (int q = 0; q < 4; ++q) {
                    const int R = rg * 32 + rt * 16 + lg * 4 + q;
                    g[R * 256 + (col ^ ((R & 7) << 3))] = f2b(lrelu(acc[rt][q]));
                }
        }
    }
    __syncthreads();

    // ---- L2: A (K=256) from g1 into regs; prefetched col loop writes g2 in-place ----
    {
        bfrag A2[2][8];
        #pragma unroll
        for (int rt = 0; rt < 2; ++rt) {
            const int r = rg * 32 + rt * 16 + lr;
            #pragma unroll
            for (int kk = 0; kk < 8; ++kk) {
                const int kc = (kk * 4 + lg) ^ (r & 7);
                A2[rt][kk] = *(const bfrag*)&g[r * 256 + kc * 8];
            }
        }
        __syncthreads();                     // g1 fully consumed into regs

        bfrag Bc[8], Bn[8];
        loadB(Bc, dw2b, (cg * 8) * 16 + lr);
        #pragma unroll
        for (int j = 0; j < 8; ++j) {
            if (j < 7) loadB(Bn, dw2b, (cg * 8 + j + 1) * 16 + lr);
            const int col = (cg * 8 + j) * 16 + lr;
            ffrag accE[2], accO[2];
            const float bv = db2[col];
            #pragma unroll
            for (int rt = 0; rt < 2; ++rt)
                #pragma unroll
                for (int q = 0; q < 4; ++q) { accE[rt][q] = bv; accO[rt][q] = 0.f; }
            #pragma unroll
            for (int kk = 0; kk < 8; kk += 2)
                #pragma unroll
                for (int rt = 0; rt < 2; ++rt) {
                    accE[rt] = __builtin_amdgcn_mfma_f32_16x16x32_bf16(A2[rt][kk],     Bc[kk],     accE[rt], 0, 0, 0);
                    accO[rt] = __builtin_amdgcn_mfma_f32_16x16x32_bf16(A2[rt][kk + 1], Bc[kk + 1], accO[rt], 0, 0, 0);
                }
            #pragma unroll
            for (int rt = 0; rt < 2; ++rt)
                #pragma unroll
                for (int q = 0; q < 4; ++q) {
                    const int R = rg * 32 + rt * 16 + lg * 4 + q;
                    g[R * 256 + (col ^ ((R & 7) << 3))] = f2b(lrelu(accE[rt][q] + accO[rt][q]));
                }
            #pragma unroll
            for (int kk = 0; kk < 8; ++kk) Bc[kk] = Bn[kk];
        }
    }
    __syncthreads();

    // ---- L3: A from g2 into regs; g becomes wave-private slabs; pipelined tile loop ----
    bfrag A3[2][8];
    #pragma unroll
    for (int rt = 0; rt < 2; ++rt) {
        const int r = rg * 32 + rt * 16 + lr;
        #pragma unroll
        for (int kk = 0; kk < 8; ++kk) {
            const int kc = (kk * 4 + lg) ^ (r & 7);
            A3[rt][kk] = *(const bfrag*)&g[r * 256 + kc * 8];
        }
    }
    __syncthreads();                         // g2 fully consumed into regs

    float* slab = (float*)g + wid * 1152;    // [32][36] fp32, wave-private

    // 49 col-tiles of 16. Pair p = tiles {2p, 2p+1} (p<24); tile 48 = tail (cg0).
    // cg waves take pairs cg, cg+2, ..., 22 (12 full pairs each); prefetch depth 1.
    bfrag Bc[8], Bn[8];
    loadB(Bc, dw3b, (2 * cg) * 16 + lr);     // first tile = 2*cg

    #pragma unroll 1
    for (int pi = 0; pi < 12; ++pi) {
        const int pair = cg + 2 * pi;
        #pragma unroll
        for (int step = 0; step < 2; ++step) {
            const int tile = 2 * pair + step;
            if (step == 0) {
                loadB(Bn, dw3b, (tile + 1) * 16 + lr);          // odd tile of this pair
            } else {
                const int np = (pair + 2 > 24) ? 24 : pair + 2;  // next even tile (or 48)
                loadB(Bn, dw3b, (2 * np) * 16 + lr);
            }
            const int col = tile * 16 + lr;
            ffrag accE[2], accO[2];
            const float bv = db3[col];
            #pragma unroll
            for (int rt = 0; rt < 2; ++rt)
                #pragma unroll
                for (int q = 0; q < 4; ++q) { accE[rt][q] = bv; accO[rt][q] = 0.f; }
            #pragma unroll
            for (int kk = 0; kk < 8; kk += 2)
                #pragma unroll
                for (int rt = 0; rt < 2; ++rt) {
                    accE[rt] = __builtin_amdgcn_mfma_f32_16x16x32_bf16(A3[rt][kk],     Bc[kk],     accE[rt], 0, 0, 0);
                    accO[rt] = __builtin_amdgcn_mfma_f32_16x16x32_bf16(A3[rt][kk + 1], Bc[kk + 1], accO[rt], 0, 0, 0);
                }
            #pragma unroll
            for (int rt = 0; rt < 2; ++rt)
                #pragma unroll
                for (int q = 0; q < 4; ++q) {
                    const int rl = rt * 16 + lg * 4 + q;
                    const float v = accE[rt][q] + accO[rt][q];
                    slab[rl * 36 + step * 16 + lr] = 1.f / (1.f + __expf(-v));
                }
            #pragma unroll
            for (int kk = 0; kk < 8; ++kk) Bc[kk] = Bn[kk];
        }
        // copy-out pair: cols pair*32..+31, rows rg*32..+31; 128B runs
        for (int f = lane; f < 256; f += 64) {
            const int row = f >> 3, c4 = f & 7;
            const float4 v = *(const float4*)&slab[row * 36 + c4 * 4];
            *(float4*)&xrec[(size_t)(pix0 + rg * 32 + row) * 784 + pair * 32 + c4 * 4] = v;
        }
    }

    if (cg == 0) {                            // tail tile 48 (cols 768..783), B already in Bc
        const int col = 768 + lr;
        ffrag accE[2], accO[2];
        const float bv = db3[col];
        #pragma unroll
        for (int rt = 0; rt < 2; ++rt)
            #pragma unroll
            for (int q = 0; q < 4; ++q) { accE[rt][q] = bv; accO[rt][q] = 0.f; }
        #pragma unroll
        for (int kk = 0; kk < 8; kk += 2)
            #pragma unroll
            for (int rt = 0; rt < 2; ++rt) {
                accE[rt] = __builtin_amdgcn_mfma_f32_16x16x32_bf16(A3[rt][kk],     Bc[kk],     accE[rt], 0, 0, 0);
                accO[rt] = __builtin_amdgcn_mfma_f32_16x16x32_bf16(A3[rt][kk + 1], Bc[kk + 1], accO[rt], 0, 0, 0);
            }
        #pragma unroll
        for (int rt = 0; rt < 2; ++rt)
            #pragma unroll
            for (int q = 0; q < 4; ++q) {
                const int rl = rt * 16 + lg * 4 + q;
                const float v = accE[rt][q] + accO[rt][q];
                slab[rl * 36 + lr] = 1.f / (1.f + __expf(-v));
            }
        for (int f = lane; f < 128; f += 64) {
            const int row = f >> 2, c4 = f & 3;
            const float4 v = *(const float4*)&slab[row * 36 + c4 * 4];
            *(float4*)&xrec[(size_t)(pix0 + rg * 32 + row) * 784 + 768 + c4 * 4] = v;
        }
    }
}

extern "C" void kernel_launch(void* const* d_in, const int* in_sizes, int n_in,
                              void* d_out, int out_size, void* d_ws, size_t ws_size,
                              hipStream_t stream) {
    const float* x    = (const float*)d_in[0];
    const float* cw1  = (const float*)d_in[1];
    const float* cb1  = (const float*)d_in[2];
    const float* cw2  = (const float*)d_in[3];
    const float* cb2  = (const float*)d_in[4];
    const float* r1w1 = (const float*)d_in[5];
    const float* r1b1 = (const float*)d_in[6];
    const float* r1w2 = (const float*)d_in[7];
    const float* r1b2 = (const float*)d_in[8];
    const float* r2w1 = (const float*)d_in[9];
    const float* r2b1 = (const float*)d_in[10];
    const float* r2w2 = (const float*)d_in[11];
    const float* r2b2 = (const float*)d_in[12];
    const float* cbk  = (const float*)d_in[13];
    const float* dw1  = (const float*)d_in[14];
    const float* db1  = (const float*)d_in[15];
    const float* dw2  = (const float*)d_in[16];
    const float* db2  = (const float*)d_in[17];
    const float* dw3  = (const float*)d_in[18];
    const float* db3  = (const float*)d_in[19];

    float* out  = (float*)d_out;
    float* xrec = out;                                   // [65536, 784]
    float* ze   = out + 51380224;                        // [64,16,32,32]
    float* zst  = ze + 1048576;
    float* zq   = zst + 1048576;

    float* A  = (float*)d_ws;                            // 3 x 4MB conv ping-pong
    float* Bf = A + (1 << 20);
    float* Cf = Bf + (1 << 20);
    short* wsb  = (short*)(Cf + (1 << 20));              // bf16 area @ +12MB
    short* zstb = wsb;                                   // [65536][16]
    short* dw2b = zstb + 1048576;
    short* dw3b = dw2b + 65536;
    short* dw1p = dw3b + 200704;                         // [256][32] zero-padded

    prep_k<<<784, 256, 0, stream>>>(dw1, dw2, dw3, dw1p, dw2b, dw3b);

    conv3_k<1,  false, false><<<1024, 256, 0, stream>>>(x,  cw1,  cb1,  nullptr, A,  nullptr, nullptr, nullptr, nullptr);
    conv3_k<16, false, false><<<1024, 256, 0, stream>>>(A,  cw2,  cb2,  nullptr, Bf, nullptr, nullptr, nullptr, nullptr);
    conv3_k<16, false, false><<<1024, 256, 0, stream>>>(Bf, r1w1, r1b1, nullptr, Cf, nullptr, nullptr, nullptr, nullptr);
    conv3_k<16, true,  false><<<1024, 256, 0, stream>>>(Cf, r1w2, r1b2, Bf, A,  nullptr, nullptr, nullptr, nullptr);
    conv3_k<16, false, false><<<1024, 256, 0, stream>>>(A,  r2w1, r2b1, nullptr, Cf, nullptr, nullptr, nullptr, nullptr);
    conv3_k<16, true,  true ><<<1024, 256, 0, stream>>>(Cf, r2w2, r2b2, A, ze, cbk, zq, zst, zstb);   // + fused VQ

    decoder_k<<<1024, 256, 0, stream>>>(zstb, dw1p, db1, dw2b, db2, dw3b, db3, xrec);
}

// Round 6
// 169.042 us; speedup vs baseline: 6.2568x; 1.3626x over previous
//
#include <hip/hip_runtime.h>

typedef __attribute__((ext_vector_type(8))) short bfrag;
typedef __attribute__((ext_vector_type(4))) float ffrag;

__device__ __forceinline__ float lrelu(float x) { return x > 0.f ? x : 0.2f * x; }

__device__ __forceinline__ short f2b(float f) {           // fp32 -> bf16 bits, RNE
    union { float f; unsigned u; } x; x.f = f;
    unsigned r = x.u + 0x7fffu + ((x.u >> 16) & 1u);
    return (short)(r >> 16);
}

// ---------------- weight prep: fp32 -> bf16 (dw1 zero-padded K 16->32) ----------------
__global__ __launch_bounds__(256) void prep_k(
    const float* __restrict__ dw1, const float* __restrict__ dw2, const float* __restrict__ dw3,
    short* __restrict__ dw1p, short* __restrict__ dw2b, short* __restrict__ dw3b)
{
    const int i = blockIdx.x * 256 + threadIdx.x;
    if (i < 65536)  dw2b[i] = f2b(dw2[i]);
    if (i < 200704) dw3b[i] = f2b(dw3[i]);
    if (i < 8192) {
        const int row = i >> 5, k = i & 31;
        dw1p[i] = (k < 16) ? f2b(dw1[row * 16 + k]) : (short)0;
    }
}

// ---------------- conv 3x3 s1 p1, NCHW. grid = 64 img x 16 bands(2 rows) ----------------
// block 256 = wpair(16) x row(2) x copair(8). Each thread: 2 px x 2 co.
// VQ=true: fused VQ epilogue (argmin + zq/zst/zstb) using the band's 64 px in LDS.
template<int CIN, bool RES, bool VQ>
__global__ __launch_bounds__(256, 6) void conv3_k(
    const float* __restrict__ in, const float* __restrict__ wgt,
    const float* __restrict__ bias, const float* __restrict__ res,
    float* __restrict__ out,
    const float* __restrict__ cbk, float* __restrict__ zq,
    float* __restrict__ zst, short* __restrict__ zstb)
{
    __shared__ float sw[16 * CIN * 9];
    __shared__ float si[CIN][4][34];            // rows band*2-1..band*2+2, cols -1..32
    __shared__ float sx[VQ ? 64 * 17 : 1];      // [px][ch] pad17
    __shared__ float scb[VQ ? 160 : 1];
    __shared__ int   sbest[VQ ? 64 : 1];

    const int t = threadIdx.x;
    const int b = blockIdx.x >> 4;
    const int band = blockIdx.x & 15;
    const float* ip = in + (size_t)b * CIN * 1024;

    for (int i = t; i < 16 * CIN * 9; i += 256) sw[i] = wgt[i];
    if (VQ) { if (t < 160) scb[t] = cbk[t]; }
    for (int i = t; i < CIN * 136; i += 256) {
        const int ci = i / 136;
        const int rem = i - ci * 136;
        const int rr = rem / 34;
        const int cc = rem - rr * 34;
        const int row = band * 2 + rr - 1;
        const int cv  = cc - 1;
        si[ci][rr][cc] = (row >= 0 && row < 32 && cv >= 0 && cv < 32)
                       ? ip[ci * 1024 + row * 32 + cv] : 0.f;
    }
    __syncthreads();

    const int w0 = (t & 15) * 2;
    const int rr = (t >> 4) & 1;
    const int co = (t >> 5) * 2;

    float acc[2][2];
    #pragma unroll
    for (int j = 0; j < 2; ++j) {
        const float bv = bias[co + j];
        acc[j][0] = bv; acc[j][1] = bv;
    }

    #pragma unroll
    for (int ci = 0; ci < CIN; ++ci)
        #pragma unroll
        for (int kh = 0; kh < 3; ++kh) {
            const float* srow = &si[ci][rr + kh][w0];   // idx m -> col w0-1+m
            float v[4];
            #pragma unroll
            for (int m = 0; m < 4; ++m) v[m] = srow[m];
            #pragma unroll
            for (int j = 0; j < 2; ++j) {
                const float* wp = &sw[((co + j) * CIN + ci) * 9 + kh * 3];
                #pragma unroll
                for (int kw = 0; kw < 3; ++kw) {
                    const float wv = wp[kw];
                    acc[j][0] = fmaf(v[kw],     wv, acc[j][0]);
                    acc[j][1] = fmaf(v[kw + 1], wv, acc[j][1]);
                }
            }
        }

    const int row = band * 2 + rr;
    #pragma unroll
    for (int j = 0; j < 2; ++j) {
        const size_t o = (size_t)b * 16384 + (size_t)(co + j) * 1024 + row * 32 + w0;
        float2 ov;
        ov.x = lrelu(acc[j][0]); ov.y = lrelu(acc[j][1]);
        if (RES) {
            const float2 rv = *(const float2*)&res[o];
            ov.x += rv.x; ov.y += rv.y;
        }
        *(float2*)&out[o] = ov;
        if (VQ) {
            sx[(rr * 32 + w0)     * 17 + co + j] = ov.x;
            sx[(rr * 32 + w0 + 1) * 17 + co + j] = ov.y;
        }
    }

    if (VQ) {
        __syncthreads();
        if (t < 64) {                          // one px per thread: argmin (first-min)
            float x[16]; float xx = 0.f;
            #pragma unroll
            for (int c = 0; c < 16; ++c) { x[c] = sx[t * 17 + c]; xx += x[c] * x[c]; }
            int best = 0; float bestd = 1e30f;
            #pragma unroll
            for (int k = 0; k < 10; ++k) {
                float dot = 0.f, cn = 0.f;
                #pragma unroll
                for (int c = 0; c < 16; ++c) { const float cv = scb[k * 16 + c]; dot += x[c] * cv; cn += cv * cv; }
                const float d2 = xx + cn - 2.f * dot;
                if (d2 < bestd) { bestd = d2; best = k; }
            }
            sbest[t] = best;
            unsigned pk[8];
            #pragma unroll
            for (int c = 0; c < 16; ++c) {
                const float q = scb[best * 16 + c];
                const float s = q + (x[c] - q);
                const unsigned hb = (unsigned)(unsigned short)f2b(s);
                if (c & 1) pk[c >> 1] |= hb << 16; else pk[c >> 1] = hb;
            }
            const size_t n = (size_t)b * 1024 + (band * 2 + (t >> 5)) * 32 + (t & 31);
            uint4* d = (uint4*)(zstb + n * 16);
            d[0] = make_uint4(pk[0], pk[1], pk[2], pk[3]);
            d[1] = make_uint4(pk[4], pk[5], pk[6], pk[7]);
        }
        __syncthreads();
        // coalesced zq/zst: 1024 elems = 16ch x 2rows x 32w, 256B runs per channel
        for (int i = t; i < 1024; i += 256) {
            const int c  = i >> 6;
            const int rw = i & 63;             // px in band
            const float q = scb[sbest[rw] * 16 + c];
            const float x = sx[rw * 17 + c];
            const size_t a = (size_t)b * 16384 + (size_t)c * 1024 + band * 64 + rw;
            zq[a]  = q;
            zst[a] = q + (x - q);
        }
    }
}

// ---------------- fused MFMA decoder: 16 -> 256 -> 256 -> 784 ----------------
// block = 256 thr = 4 waves, 128 px; each wave owns 32 rows, full K in registers.
// LDS: 4 x 16KB wave-private g (g1 -> g2 in-place -> fp32 slab), 2 x 8KB B-panel dbuf.
// L2+L3 = unified 65-panel pipeline: stage(p+1 via global_load_lds, inv-swizzled src)
// -> compute panel p from LDS -> barrier. A always in regs, no inter-wave exchange.
__global__ __launch_bounds__(256, 2) void decoder_k(
    const short* __restrict__ zstb,
    const short* __restrict__ dw1p, const float* __restrict__ db1,
    const short* __restrict__ dw2b, const float* __restrict__ db2,
    const short* __restrict__ dw3b, const float* __restrict__ db3,
    float* __restrict__ xrec)
{
    __shared__ short g[4 * 8192];            // 64 KB: per-wave [32][256] bf16, swizzled
    __shared__ short b3[2][4096];            // 16 KB: B panel [16 out][256 k] dbuf, swizzled

    const int t    = threadIdx.x;
    const int lane = t & 63;
    const int wid  = t >> 6;
    const int lr   = lane & 15;
    const int lg   = lane >> 4;
    const int row0 = blockIdx.x * 128 + wid * 32;     // wave's first pixel
    short* gw = g + wid * 8192;

    // swizzled byte offset in a [rows][512B] tile: spreads rows over banks
    #define GB(row, kbyte) (((row) * 512 + (kbyte)) ^ (((row) & 7) << 4))

    // stage one 8KB panel (16 out-rows x 256 k bf16) into LDS, source inverse-swizzled
    auto stage2 = [&](short* dst, const short* src) {
        #pragma unroll
        for (int h = 0; h < 2; ++h) {
            const int L = h * 4096 + t * 16;                       // lds byte, linear
            const int S = L ^ (((L >> 9) & 7) << 4);               // swizzled source byte
            __builtin_amdgcn_global_load_lds(
                (const __attribute__((address_space(1))) void*)((const char*)src + S),
                (__attribute__((address_space(3))) void*)((char*)dst + L), 16, 0, 0);
        }
    };

    // issue first B-panel (dw2b panel 0) right away; lands during L1
    stage2(&b3[0][0], dw2b);

    // ---- L1: A1 straight from global (K=16, upper half zero), write g1 (wave-private) ----
    {
        bfrag A1[2];
        #pragma unroll
        for (int rt = 0; rt < 2; ++rt) {
            bfrag z;
            #pragma unroll
            for (int i = 0; i < 8; ++i) z[i] = 0;
            if (lg < 2)
                z = *(const bfrag*)&zstb[(size_t)(row0 + rt * 16 + lr) * 16 + lg * 8];
            A1[rt] = z;
        }
        #pragma unroll
        for (int ct = 0; ct < 16; ++ct) {
            const int col = ct * 16 + lr;
            const bfrag B = *(const bfrag*)&dw1p[col * 32 + lg * 8];
            const float bv = db1[col];
            ffrag acc[2];
            #pragma unroll
            for (int rt = 0; rt < 2; ++rt) {
                #pragma unroll
                for (int q = 0; q < 4; ++q) acc[rt][q] = bv;
                acc[rt] = __builtin_amdgcn_mfma_f32_16x16x32_bf16(A1[rt], B, acc[rt], 0, 0, 0);
            }
            #pragma unroll
            for (int rt = 0; rt < 2; ++rt)
                #pragma unroll
                for (int q = 0; q < 4; ++q) {
                    const int R = rt * 16 + lg * 4 + q;
                    *(short*)((char*)gw + GB(R, col * 2)) = f2b(lrelu(acc[rt][q]));
                }
        }
    }

    // ---- A2 from g1 (wave-local, no barrier) ----
    bfrag A[2][8];
    #pragma unroll
    for (int rt = 0; rt < 2; ++rt)
        #pragma unroll
        for (int kk = 0; kk < 8; ++kk)
            A[rt][kk] = *(const bfrag*)((char*)gw + GB(rt * 16 + lr, kk * 64 + lg * 16));

    __syncthreads();                          // b3[0] staged (vmcnt drained)

    // ---- L2: 16 panels of dw2b from LDS dbuf; g2 written in-place over g1 ----
    #pragma unroll 1
    for (int p = 0; p < 16; ++p) {
        if (p < 15) stage2(&b3[(p + 1) & 1][0], dw2b + (p + 1) * 4096);
        else        stage2(&b3[0][0],           dw3b);               // dw3b panel 0
        const char* bp = (const char*)&b3[p & 1][0];
        const int col = p * 16 + lr;
        bfrag Bf[8];
        #pragma unroll
        for (int kk = 0; kk < 8; ++kk)
            Bf[kk] = *(const bfrag*)(bp + (((lr * 512 + kk * 64 + lg * 16)) ^ ((lr & 7) << 4)));
        ffrag aE[2], aO[2];
        const float bv = db2[col];
        #pragma unroll
        for (int rt = 0; rt < 2; ++rt)
            #pragma unroll
            for (int q = 0; q < 4; ++q) { aE[rt][q] = bv; aO[rt][q] = 0.f; }
        #pragma unroll
        for (int kk = 0; kk < 8; kk += 2)
            #pragma unroll
            for (int rt = 0; rt < 2; ++rt) {
                aE[rt] = __builtin_amdgcn_mfma_f32_16x16x32_bf16(A[rt][kk],     Bf[kk],     aE[rt], 0, 0, 0);
                aO[rt] = __builtin_amdgcn_mfma_f32_16x16x32_bf16(A[rt][kk + 1], Bf[kk + 1], aO[rt], 0, 0, 0);
            }
        #pragma unroll
        for (int rt = 0; rt < 2; ++rt)
            #pragma unroll
            for (int q = 0; q < 4; ++q) {
                const int R = rt * 16 + lg * 4 + q;
                *(short*)((char*)gw + GB(R, col * 2)) = f2b(lrelu(aE[rt][q] + aO[rt][q]));
            }
        __syncthreads();
    }

    // ---- A3 from g2 (wave-local), then g region becomes this wave's fp32 slab ----
    #pragma unroll
    for (int rt = 0; rt < 2; ++rt)
        #pragma unroll
        for (int kk = 0; kk < 8; ++kk)
            A[rt][kk] = *(const bfrag*)((char*)gw + GB(rt * 16 + lr, kk * 64 + lg * 16));

    float* slab = (float*)gw;                 // [32][36] fp32 (4608B < 16KB)

    // ---- L3: 49 panels of dw3b; sigmoid -> slab; paired 128B-run writes ----
    #pragma unroll 1
    for (int p = 0; p < 49; ++p) {
        if (p < 48) stage2(&b3[(p + 1) & 1][0], dw3b + (p + 1) * 4096);
        const char* bp = (const char*)&b3[p & 1][0];
        const int col = p * 16 + lr;
        bfrag Bf[8];
        #pragma unroll
        for (int kk = 0; kk < 8; ++kk)
            Bf[kk] = *(const bfrag*)(bp + (((lr * 512 + kk * 64 + lg * 16)) ^ ((lr & 7) << 4)));
        ffrag aE[2], aO[2];
        const float bv = db3[col];
        #pragma unroll
        for (int rt = 0; rt < 2; ++rt)
            #pragma unroll
            for (int q = 0; q < 4; ++q) { aE[rt][q] = bv; aO[rt][q] = 0.f; }
        #pragma unroll
        for (int kk = 0; kk < 8; kk += 2)
            #pragma unroll
            for (int rt = 0; rt < 2; ++rt) {
                aE[rt] = __builtin_amdgcn_mfma_f32_16x16x32_bf16(A[rt][kk],     Bf[kk],     aE[rt], 0, 0, 0);
                aO[rt] = __builtin_amdgcn_mfma_f32_16x16x32_bf16(A[rt][kk + 1], Bf[kk + 1], aO[rt], 0, 0, 0);
            }
        const int ph = p & 1;
        #pragma unroll
        for (int rt = 0; rt < 2; ++rt)
            #pragma unroll
            for (int q = 0; q < 4; ++q) {
                const int R = rt * 16 + lg * 4 + q;
                const float v = aE[rt][q] + aO[rt][q];
                slab[R * 36 + ph * 16 + lr] = 1.f / (1.f + __expf(-v));
            }
        if (ph) {                              // write pair (p-1,p): 32 cols, 128B runs
            const int cb = (p - 1) * 16;
            #pragma unroll
            for (int f0 = 0; f0 < 4; ++f0) {
                const int f = f0 * 64 + lane;
                const int row = f >> 3, c4 = f & 7;
                const float4 v = *(const float4*)&slab[row * 36 + c4 * 4];
                *(float4*)&xrec[(size_t)(row0 + row) * 784 + cb + c4 * 4] = v;
            }
        }
        if (p == 48) {                         // tail tile: cols 768..783 (64B runs)
            #pragma unroll
            for (int f0 = 0; f0 < 2; ++f0) {
                const int f = f0 * 64 + lane;
                const int row = f >> 2, c4 = f & 3;
                const float4 v = *(const float4*)&slab[row * 36 + c4 * 4];
                *(float4*)&xrec[(size_t)(row0 + row) * 784 + 768 + c4 * 4] = v;
            }
        }
        __syncthreads();
    }
    #undef GB
}

extern "C" void kernel_launch(void* const* d_in, const int* in_sizes, int n_in,
                              void* d_out, int out_size, void* d_ws, size_t ws_size,
                              hipStream_t stream) {
    const float* x    = (const float*)d_in[0];
    const float* cw1  = (const float*)d_in[1];
    const float* cb1  = (const float*)d_in[2];
    const float* cw2  = (const float*)d_in[3];
    const float* cb2  = (const float*)d_in[4];
    const float* r1w1 = (const float*)d_in[5];
    const float* r1b1 = (const float*)d_in[6];
    const float* r1w2 = (const float*)d_in[7];
    const float* r1b2 = (const float*)d_in[8];
    const float* r2w1 = (const float*)d_in[9];
    const float* r2b1 = (const float*)d_in[10];
    const float* r2w2 = (const float*)d_in[11];
    const float* r2b2 = (const float*)d_in[12];
    const float* cbk  = (const float*)d_in[13];
    const float* dw1  = (const float*)d_in[14];
    const float* db1  = (const float*)d_in[15];
    const float* dw2  = (const float*)d_in[16];
    const float* db2  = (const float*)d_in[17];
    const float* dw3  = (const float*)d_in[18];
    const float* db3  = (const float*)d_in[19];

    float* out  = (float*)d_out;
    float* xrec = out;                                   // [65536, 784]
    float* ze   = out + 51380224;                        // [64,16,32,32]
    float* zst  = ze + 1048576;
    float* zq   = zst + 1048576;

    float* A  = (float*)d_ws;                            // 3 x 4MB conv ping-pong
    float* Bf = A + (1 << 20);
    float* Cf = Bf + (1 << 20);
    short* wsb  = (short*)(Cf + (1 << 20));              // bf16 area @ +12MB
    short* zstb = wsb;                                   // [65536][16]
    short* dw2b = zstb + 1048576;
    short* dw3b = dw2b + 65536;
    short* dw1p = dw3b + 200704;                         // [256][32] zero-padded

    prep_k<<<784, 256, 0, stream>>>(dw1, dw2, dw3, dw1p, dw2b, dw3b);

    conv3_k<1,  false, false><<<1024, 256, 0, stream>>>(x,  cw1,  cb1,  nullptr, A,  nullptr, nullptr, nullptr, nullptr);
    conv3_k<16, false, false><<<1024, 256, 0, stream>>>(A,  cw2,  cb2,  nullptr, Bf, nullptr, nullptr, nullptr, nullptr);
    conv3_k<16, false, false><<<1024, 256, 0, stream>>>(Bf, r1w1, r1b1, nullptr, Cf, nullptr, nullptr, nullptr, nullptr);
    conv3_k<16, true,  false><<<1024, 256, 0, stream>>>(Cf, r1w2, r1b2, Bf, A,  nullptr, nullptr, nullptr, nullptr);
    conv3_k<16, false, false><<<1024, 256, 0, stream>>>(A,  r2w1, r2b1, nullptr, Cf, nullptr, nullptr, nullptr, nullptr);
    conv3_k<16, true,  true ><<<1024, 256, 0, stream>>>(Cf, r2w2, r2b2, A, ze, cbk, zq, zst, zstb);   // + fused VQ

    decoder_k<<<512, 256, 0, stream>>>(zstb, dw1p, db1, dw2b, db2, dw3b, db3, xrec);
}

// Round 7
// 156.017 us; speedup vs baseline: 6.7792x; 1.0835x over previous
//
#include <hip/hip_runtime.h>

typedef __attribute__((ext_vector_type(8))) short bfrag;
typedef __attribute__((ext_vector_type(4))) float ffrag;

__device__ __forceinline__ float lrelu(float x) { return x > 0.f ? x : 0.2f * x; }

__device__ __forceinline__ short f2b(float f) {           // fp32 -> bf16 bits, RNE
    union { float f; unsigned u; } x; x.f = f;
    unsigned r = x.u + 0x7fffu + ((x.u >> 16) & 1u);
    return (short)(r >> 16);
}

// ---------------- prep: bf16 decoder weights + transposed conv weights ----------------
// wtr[s][(ci*9+k)*16+co] : conv weights transposed to ci-major, co-contiguous (s_load16)
__global__ __launch_bounds__(256) void prep_k(
    const float* __restrict__ dw1, const float* __restrict__ dw2, const float* __restrict__ dw3,
    const float* __restrict__ cw1, const float* __restrict__ cw2,
    const float* __restrict__ r1w1, const float* __restrict__ r1w2,
    const float* __restrict__ r2w1, const float* __restrict__ r2w2,
    short* __restrict__ dw1p, short* __restrict__ dw2b, short* __restrict__ dw3b,
    float* __restrict__ wtr)
{
    const int i = blockIdx.x * 256 + threadIdx.x;
    if (i < 65536)  dw2b[i] = f2b(dw2[i]);
    if (i < 200704) dw3b[i] = f2b(dw3[i]);
    if (i < 8192) {
        const int row = i >> 5, k = i & 31;
        dw1p[i] = (k < 16) ? f2b(dw1[row * 16 + k]) : (short)0;
    }
    if (i < 2304) {
        const int co = i & 15;
        const int q  = i >> 4;
        const int k  = q % 9;
        const int ci = q / 9;
        const int src = (co * 16 + ci) * 9 + k;
        wtr[2304 * 1 + i] = cw2 [src];
        wtr[2304 * 2 + i] = r1w1[src];
        wtr[2304 * 3 + i] = r1w2[src];
        wtr[2304 * 4 + i] = r2w1[src];
        wtr[2304 * 5 + i] = r2w2[src];
        if (ci == 0) wtr[i] = cw1[co * 9 + k];
    }
}

// ---------------- fused encoder: 6 convs + VQ, one block per (image, 8-row band) ----------
// 512 threads. Thread = 1 px x 16 cout (weights via SGPR s_loads, LDS only for activations).
// LDS buffers hold haloed bands; halo shrinks by 1 row per conv. Layout [co][R][36] fp32.
template<int CIN, int RIN, int ROUT, int HOUT, bool HASRES, int RRES, int HRES>
__device__ __forceinline__ void conv_stage(
    const float* __restrict__ in, float* __restrict__ out, const float* __restrict__ res,
    const float* __restrict__ wt, const float* __restrict__ bias, int r0, int t)
{
    const int lo = (r0 - HOUT > 0) ? r0 - HOUT : 0;
    const int hi = (r0 + 8 + HOUT < 32) ? r0 + 8 + HOUT : 32;
    const int base = r0 - HOUT;
    const int nlow = lo - base;              // out-of-image rows at top
    const int hih  = hi - base;              // first out-of-image row at bottom
    if (nlow > 0 || hih < ROUT) {            // edge bands only: zero pad rows
        const int nz = (nlow + (ROUT - hih)) * 36;
        for (int i = t; i < 16 * nz; i += 512) {
            const int ch = i / nz, rem = i % nz;
            int r = rem / 36; const int c = rem % 36;
            r = (r < nlow) ? r : (hih + (r - nlow));
            out[(ch * ROUT + r) * 36 + c] = 0.f;
        }
    }
    for (int i = t; i < 16 * ROUT * 2; i += 512) {   // zero pad cols 0 and 33
        const int ch = i / (ROUT * 2), rem = i % (ROUT * 2);
        out[(ch * ROUT + (rem >> 1)) * 36 + ((rem & 1) ? 33 : 0)] = 0.f;
    }

    const int n = (hi - lo) * 32;
    for (int u = t; u < n; u += 512) {
        const int row = lo + (u >> 5), col = u & 31;
        const int prin = row - r0 + HOUT;            // phys input row for kh=0
        float acc[16];
        #pragma unroll
        for (int co = 0; co < 16; ++co) acc[co] = bias[co];
        for (int ci = 0; ci < CIN; ++ci) {
            const float* ip = in + (ci * RIN + prin) * 36 + col;
            float v[9];
            #pragma unroll
            for (int kh = 0; kh < 3; ++kh)
                #pragma unroll
                for (int kw = 0; kw < 3; ++kw) v[kh * 3 + kw] = ip[kh * 36 + kw];
            const float* wp = wt + ci * 144;         // [9][16co], block-uniform -> s_load
            #pragma unroll
            for (int k = 0; k < 9; ++k)
                #pragma unroll
                for (int co = 0; co < 16; ++co)
                    acc[co] = fmaf(v[k], wp[k * 16 + co], acc[co]);
        }
        const int pro = row - base;
        #pragma unroll
        for (int co = 0; co < 16; ++co) {
            float val = lrelu(acc[co]);
            if (HASRES) val += res[(co * RRES + (row - (r0 - HRES))) * 36 + col + 1];
            out[(co * ROUT + pro) * 36 + col + 1] = val;
        }
    }
    __syncthreads();
}

__global__ __launch_bounds__(512, 1) void enc_k(
    const float* __restrict__ x, const float* __restrict__ wtr,
    const float* __restrict__ cb1, const float* __restrict__ cb2,
    const float* __restrict__ r1b1, const float* __restrict__ r1b2,
    const float* __restrict__ r2b1, const float* __restrict__ r2b2,
    const float* __restrict__ cbk,
    float* __restrict__ ze, float* __restrict__ zq,
    float* __restrict__ zst, short* __restrict__ zstb)
{
    __shared__ float xb[20 * 36];
    __shared__ float Abuf[16 * 18 * 36];
    __shared__ float Bbuf[16 * 16 * 36];
    __shared__ float Cbuf[16 * 12 * 36];
    __shared__ float scb[160];
    __shared__ int   sbest[256];

    const int t  = threadIdx.x;
    const int b  = blockIdx.x >> 2;
    const int r0 = (blockIdx.x & 3) * 8;

    if (t < 160) scb[t] = cbk[t];
    for (int i = t; i < 720; i += 512) {             // x band rows r0-6 .. r0+13, zero-padded
        const int r = i / 36, c = i % 36;
        const int rl = r0 - 6 + r, cl = c - 1;
        xb[i] = (rl >= 0 && rl < 32 && cl >= 0 && cl < 32)
              ? x[(size_t)b * 1024 + rl * 32 + cl] : 0.f;
    }
    __syncthreads();

    conv_stage<1,  20, 18, 5, false,  1, 0>(xb,   Abuf, nullptr, wtr,          cb1,  r0, t); // s1
    conv_stage<16, 18, 16, 4, false,  1, 0>(Abuf, Bbuf, nullptr, wtr + 2304,   cb2,  r0, t); // s2
    conv_stage<16, 16, 14, 3, false,  1, 0>(Bbuf, Abuf, nullptr, wtr + 4608,   r1b1, r0, t); // t1
    conv_stage<16, 14, 12, 2, true,  16, 4>(Abuf, Cbuf, Bbuf,    wtr + 6912,   r1b2, r0, t); // h3 = lrelu+s2
    conv_stage<16, 12, 10, 1, false,  1, 0>(Cbuf, Abuf, nullptr, wtr + 9216,   r2b1, r0, t); // t2
    conv_stage<16, 10,  8, 0, true,  12, 2>(Abuf, Bbuf, Cbuf,    wtr + 11520,  r2b2, r0, t); // z_e = lrelu+h3

    // ---- z_e -> global (NCHW, 1KB runs per channel) ----
    const size_t obase = (size_t)b * 16384 + r0 * 32;
    for (int i = t; i < 4096; i += 512) {
        const int c = i >> 8, px = i & 255;
        ze[obase + c * 1024 + px] = Bbuf[(c * 8 + (px >> 5)) * 36 + (px & 31) + 1];
    }
    // ---- VQ argmin (first-min) + zstb pack, one px per thread ----
    if (t < 256) {
        const int r = t >> 5, col = t & 31;
        float xv[16]; float xx = 0.f;
        #pragma unroll
        for (int c = 0; c < 16; ++c) { xv[c] = Bbuf[(c * 8 + r) * 36 + col + 1]; xx += xv[c] * xv[c]; }
        int best = 0; float bestd = 1e30f;
        #pragma unroll
        for (int k = 0; k < 10; ++k) {
            float dot = 0.f, cn = 0.f;
            #pragma unroll
            for (int c = 0; c < 16; ++c) { const float cv = scb[k * 16 + c]; dot += xv[c] * cv; cn += cv * cv; }
            const float d2 = xx + cn - 2.f * dot;
            if (d2 < bestd) { bestd = d2; best = k; }
        }
        sbest[t] = best;
        unsigned pk[8];
        #pragma unroll
        for (int c = 0; c < 16; ++c) {
            const float q = scb[best * 16 + c];
            const float s = q + (xv[c] - q);
            const unsigned hb = (unsigned)(unsigned short)f2b(s);
            if (c & 1) pk[c >> 1] |= hb << 16; else pk[c >> 1] = hb;
        }
        const size_t n = (size_t)b * 1024 + (size_t)(r0 + r) * 32 + col;
        uint4* d = (uint4*)(zstb + n * 16);
        d[0] = make_uint4(pk[0], pk[1], pk[2], pk[3]);
        d[1] = make_uint4(pk[4], pk[5], pk[6], pk[7]);
    }
    __syncthreads();
    // ---- zq / zst (fp32, coalesced) ----
    for (int i = t; i < 4096; i += 512) {
        const int c = i >> 8, px = i & 255;
        const float q  = scb[sbest[px] * 16 + c];
        const float xv = Bbuf[(c * 8 + (px >> 5)) * 36 + (px & 31) + 1];
        zq[obase + c * 1024 + px]  = q;
        zst[obase + c * 1024 + px] = q + (xv - q);
    }
}

// ---------------- fused MFMA decoder: 16 -> 256 -> 256 -> 784 (unchanged, round 6) ---------
__global__ __launch_bounds__(256, 2) void decoder_k(
    const short* __restrict__ zstb,
    const short* __restrict__ dw1p, const float* __restrict__ db1,
    const short* __restrict__ dw2b, const float* __restrict__ db2,
    const short* __restrict__ dw3b, const float* __restrict__ db3,
    float* __restrict__ xrec)
{
    __shared__ short g[4 * 8192];            // 64 KB: per-wave [32][256] bf16, swizzled
    __shared__ short b3[2][4096];            // 16 KB: B panel [16 out][256 k] dbuf, swizzled

    const int t    = threadIdx.x;
    const int lane = t & 63;
    const int wid  = t >> 6;
    const int lr   = lane & 15;
    const int lg   = lane >> 4;
    const int row0 = blockIdx.x * 128 + wid * 32;     // wave's first pixel
    short* gw = g + wid * 8192;

    #define GB(row, kbyte) (((row) * 512 + (kbyte)) ^ (((row) & 7) << 4))

    auto stage2 = [&](short* dst, const short* src) {
        #pragma unroll
        for (int h = 0; h < 2; ++h) {
            const int L = h * 4096 + t * 16;                       // lds byte, linear
            const int S = L ^ (((L >> 9) & 7) << 4);               // swizzled source byte
            __builtin_amdgcn_global_load_lds(
                (const __attribute__((address_space(1))) void*)((const char*)src + S),
                (__attribute__((address_space(3))) void*)((char*)dst + L), 16, 0, 0);
        }
    };

    stage2(&b3[0][0], dw2b);

    // ---- L1 ----
    {
        bfrag A1[2];
        #pragma unroll
        for (int rt = 0; rt < 2; ++rt) {
            bfrag z;
            #pragma unroll
            for (int i = 0; i < 8; ++i) z[i] = 0;
            if (lg < 2)
                z = *(const bfrag*)&zstb[(size_t)(row0 + rt * 16 + lr) * 16 + lg * 8];
            A1[rt] = z;
        }
        #pragma unroll
        for (int ct = 0; ct < 16; ++ct) {
            const int col = ct * 16 + lr;
            const bfrag B = *(const bfrag*)&dw1p[col * 32 + lg * 8];
            const float bv = db1[col];
            ffrag acc[2];
            #pragma unroll
            for (int rt = 0; rt < 2; ++rt) {
                #pragma unroll
                for (int q = 0; q < 4; ++q) acc[rt][q] = bv;
                acc[rt] = __builtin_amdgcn_mfma_f32_16x16x32_bf16(A1[rt], B, acc[rt], 0, 0, 0);
            }
            #pragma unroll
            for (int rt = 0; rt < 2; ++rt)
                #pragma unroll
                for (int q = 0; q < 4; ++q) {
                    const int R = rt * 16 + lg * 4 + q;
                    *(short*)((char*)gw + GB(R, col * 2)) = f2b(lrelu(acc[rt][q]));
                }
        }
    }

    bfrag A[2][8];
    #pragma unroll
    for (int rt = 0; rt < 2; ++rt)
        #pragma unroll
        for (int kk = 0; kk < 8; ++kk)
            A[rt][kk] = *(const bfrag*)((char*)gw + GB(rt * 16 + lr, kk * 64 + lg * 16));

    __syncthreads();                          // b3[0] staged

    // ---- L2 ----
    #pragma unroll 1
    for (int p = 0; p < 16; ++p) {
        if (p < 15) stage2(&b3[(p + 1) & 1][0], dw2b + (p + 1) * 4096);
        else        stage2(&b3[0][0],           dw3b);
        const char* bp = (const char*)&b3[p & 1][0];
        const int col = p * 16 + lr;
        bfrag Bf[8];
        #pragma unroll
        for (int kk = 0; kk < 8; ++kk)
            Bf[kk] = *(const bfrag*)(bp + (((lr * 512 + kk * 64 + lg * 16)) ^ ((lr & 7) << 4)));
        ffrag aE[2], aO[2];
        const float bv = db2[col];
        #pragma unroll
        for (int rt = 0; rt < 2; ++rt)
            #pragma unroll
            for (int q = 0; q < 4; ++q) { aE[rt][q] = bv; aO[rt][q] = 0.f; }
        #pragma unroll
        for (int kk = 0; kk < 8; kk += 2)
            #pragma unroll
            for (int rt = 0; rt < 2; ++rt) {
                aE[rt] = __builtin_amdgcn_mfma_f32_16x16x32_bf16(A[rt][kk],     Bf[kk],     aE[rt], 0, 0, 0);
                aO[rt] = __builtin_amdgcn_mfma_f32_16x16x32_bf16(A[rt][kk + 1], Bf[kk + 1], aO[rt], 0, 0, 0);
            }
        #pragma unroll
        for (int rt = 0; rt < 2; ++rt)
            #pragma unroll
            for (int q = 0; q < 4; ++q) {
                const int R = rt * 16 + lg * 4 + q;
                *(short*)((char*)gw + GB(R, col * 2)) = f2b(lrelu(aE[rt][q] + aO[rt][q]));
            }
        __syncthreads();
    }

    #pragma unroll
    for (int rt = 0; rt < 2; ++rt)
        #pragma unroll
        for (int kk = 0; kk < 8; ++kk)
            A[rt][kk] = *(const bfrag*)((char*)gw + GB(rt * 16 + lr, kk * 64 + lg * 16));

    float* slab = (float*)gw;                 // [32][36] fp32

    // ---- L3 ----
    #pragma unroll 1
    for (int p = 0; p < 49; ++p) {
        if (p < 48) stage2(&b3[(p + 1) & 1][0], dw3b + (p + 1) * 4096);
        const char* bp = (const char*)&b3[p & 1][0];
        const int col = p * 16 + lr;
        bfrag Bf[8];
        #pragma unroll
        for (int kk = 0; kk < 8; ++kk)
            Bf[kk] = *(const bfrag*)(bp + (((lr * 512 + kk * 64 + lg * 16)) ^ ((lr & 7) << 4)));
        ffrag aE[2], aO[2];
        const float bv = db3[col];
        #pragma unroll
        for (int rt = 0; rt < 2; ++rt)
            #pragma unroll
            for (int q = 0; q < 4; ++q) { aE[rt][q] = bv; aO[rt][q] = 0.f; }
        #pragma unroll
        for (int kk = 0; kk < 8; kk += 2)
            #pragma unroll
            for (int rt = 0; rt < 2; ++rt) {
                aE[rt] = __builtin_amdgcn_mfma_f32_16x16x32_bf16(A[rt][kk],     Bf[kk],     aE[rt], 0, 0, 0);
                aO[rt] = __builtin_amdgcn_mfma_f32_16x16x32_bf16(A[rt][kk + 1], Bf[kk + 1], aO[rt], 0, 0, 0);
            }
        const int ph = p & 1;
        #pragma unroll
        for (int rt = 0; rt < 2; ++rt)
            #pragma unroll
            for (int q = 0; q < 4; ++q) {
                const int R = rt * 16 + lg * 4 + q;
                const float v = aE[rt][q] + aO[rt][q];
                slab[R * 36 + ph * 16 + lr] = 1.f / (1.f + __expf(-v));
            }
        if (ph) {
            const int cb = (p - 1) * 16;
            #pragma unroll
            for (int f0 = 0; f0 < 4; ++f0) {
                const int f = f0 * 64 + lane;
                const int row = f >> 3, c4 = f & 7;
                const float4 v = *(const float4*)&slab[row * 36 + c4 * 4];
                *(float4*)&xrec[(size_t)(row0 + row) * 784 + cb + c4 * 4] = v;
            }
        }
        if (p == 48) {
            #pragma unroll
            for (int f0 = 0; f0 < 2; ++f0) {
                const int f = f0 * 64 + lane;
                const int row = f >> 2, c4 = f & 3;
                const float4 v = *(const float4*)&slab[row * 36 + c4 * 4];
                *(float4*)&xrec[(size_t)(row0 + row) * 784 + 768 + c4 * 4] = v;
            }
        }
        __syncthreads();
    }
    #undef GB
}

extern "C" void kernel_launch(void* const* d_in, const int* in_sizes, int n_in,
                              void* d_out, int out_size, void* d_ws, size_t ws_size,
                              hipStream_t stream) {
    const float* x    = (const float*)d_in[0];
    const float* cw1  = (const float*)d_in[1];
    const float* cb1  = (const float*)d_in[2];
    const float* cw2  = (const float*)d_in[3];
    const float* cb2  = (const float*)d_in[4];
    const float* r1w1 = (const float*)d_in[5];
    const float* r1b1 = (const float*)d_in[6];
    const float* r1w2 = (const float*)d_in[7];
    const float* r1b2 = (const float*)d_in[8];
    const float* r2w1 = (const float*)d_in[9];
    const float* r2b1 = (const float*)d_in[10];
    const float* r2w2 = (const float*)d_in[11];
    const float* r2b2 = (const float*)d_in[12];
    const float* cbk  = (const float*)d_in[13];
    const float* dw1  = (const float*)d_in[14];
    const float* db1  = (const float*)d_in[15];
    const float* dw2  = (const float*)d_in[16];
    const float* db2  = (const float*)d_in[17];
    const float* dw3  = (const float*)d_in[18];
    const float* db3  = (const float*)d_in[19];

    float* out  = (float*)d_out;
    float* xrec = out;                                   // [65536, 784]
    float* ze   = out + 51380224;                        // [64,16,32,32]
    float* zst  = ze + 1048576;
    float* zq   = zst + 1048576;

    short* zstb = (short*)d_ws;                          // [65536][16] bf16
    short* dw2b = zstb + 1048576;
    short* dw3b = dw2b + 65536;
    short* dw1p = dw3b + 200704;                         // [256][32] zero-padded
    float* wtr  = (float*)(dw1p + 8192);                 // [6][2304] transposed conv w

    prep_k<<<784, 256, 0, stream>>>(dw1, dw2, dw3, cw1, cw2, r1w1, r1w2, r2w1, r2w2,
                                    dw1p, dw2b, dw3b, wtr);

    enc_k<<<256, 512, 0, stream>>>(x, wtr, cb1, cb2, r1b1, r1b2, r2b1, r2b2,
                                   cbk, ze, zq, zst, zstb);

    decoder_k<<<512, 256, 0, stream>>>(zstb, dw1p, db1, dw2b, db2, dw3b, db3, xrec);
}